// Round 10
// baseline (308.568 us; speedup 1.0000x reference)
//
#include <hip/hip_runtime.h>
#include <hip/hip_bf16.h>

#define NGRAPHS 64
#define RANGE 8192   // nodes per LDS histogram range (32 KB)
#define CHUNKS 16    // deterministic edge chunks (per-chunk count/cursor copies)

typedef unsigned short bf16_t;
using s8v = __attribute__((ext_vector_type(8))) short;   // 8 bf16 (4 VGPRs)
using f4v = __attribute__((ext_vector_type(4))) float;   // MFMA accumulator

__device__ inline float bf2f(bf16_t u) { return __uint_as_float(((unsigned)u) << 16); }
__device__ inline bf16_t f2bf(float f) {
    unsigned x = __float_as_uint(f);
    return (bf16_t)((x + 0x7fffu + ((x >> 16) & 1u)) >> 16);  // RNE
}

// ============ CSR build: LDS histograms, ZERO global atomics ============

// blockIdx.x = type*nr*CHUNKS + r*CHUNKS + c
// type 0: in-degree histogram over dst -> cntC_in[c][...]
// type 1: out-degree histogram over src -> cntC_out[c][...]
__global__ void k_hist(const int* __restrict__ src, const int* __restrict__ dst,
                       int* __restrict__ cntC_in, int* __restrict__ cntC_out,
                       int nr, int n, int E) {
    __shared__ int hist[RANGE];
    int bid = blockIdx.x;
    int type = bid / (nr * CHUNKS);
    int rem = bid - type * nr * CHUNKS;
    int r = rem / CHUNKS, c = rem - r * CHUNKS;
    const int* __restrict__ keys = type ? src : dst;
    int* __restrict__ outbuf = type ? cntC_out : cntC_in;

    for (int i = threadIdx.x; i < RANGE; i += 256) hist[i] = 0;
    __syncthreads();

    int lo = r * RANGE;
    int e0 = (E / CHUNKS) * c;
    int e1 = (c == CHUNKS - 1) ? E : e0 + E / CHUNKS;
    for (int e = e0 + threadIdx.x; e < e1; e += 256) {
        int k = keys[e] - lo;
        if ((unsigned)k < (unsigned)RANGE) atomicAdd(&hist[k], 1);
    }
    __syncthreads();

    int hi = min(n - lo, RANGE);
    for (int i = threadIdx.x; i < hi; i += 256)
        outbuf[(size_t)c * n + lo + i] = hist[i];   // plain store, each elem owned once
}

__device__ inline int block_excl_scan(int v, int tid, int* wavesums, int* block_total) {
    int lane = tid & 63, wave = tid >> 6;
    int incl = v;
    #pragma unroll
    for (int off = 1; off < 64; off <<= 1) {
        int t = __shfl_up(incl, off);
        if (lane >= off) incl += t;
    }
    if (lane == 63) wavesums[wave] = incl;
    __syncthreads();
    int woff = 0;
    #pragma unroll
    for (int w = 0; w < 4; ++w) if (w < wave) woff += wavesums[w];
    *block_total = wavesums[0] + wavesums[1] + wavesums[2] + wavesums[3];
    return incl + woff - v;
}

// sum CHUNKS in-count copies -> cnt_tot_in; block-local exclusive scan -> rowptr
__global__ void k_scan1(const int* __restrict__ cntC_in, int* __restrict__ cnt_tot_in,
                        int* __restrict__ rowptr, int* __restrict__ blocksums, int n) {
    __shared__ int wavesums[4];
    int tid = threadIdx.x;
    int idx = blockIdx.x * 256 + tid;
    int v = 0;
    if (idx < n) {
        #pragma unroll
        for (int k = 0; k < CHUNKS; ++k) v += cntC_in[(size_t)k * n + idx];
        cnt_tot_in[idx] = v;
    }
    int total;
    int excl = block_excl_scan(v, tid, wavesums, &total);
    if (idx < n) rowptr[idx] = excl;
    if (tid == 0) blocksums[blockIdx.x] = total;
}

__global__ void k_scan2(int* __restrict__ blocksums, int nb) {
    __shared__ int wavesums[4];
    int tid = threadIdx.x;
    int v = (tid < nb) ? blocksums[tid] : 0;
    int total;
    int excl = block_excl_scan(v, tid, wavesums, &total);
    if (tid < nb) blocksums[tid] = excl;
}

// finalize rowptr; per-chunk cursor bases; fused norms + layer-0 src vals
__global__ void k_scan3(int* __restrict__ rowptr, const int* __restrict__ blocksums,
                        const int* __restrict__ cntC_in, const int* __restrict__ cntC_out,
                        const int* __restrict__ cnt_tot_in,
                        int* __restrict__ cursorC,
                        float* __restrict__ norm_src, float* __restrict__ norm_dst,
                        float* __restrict__ vsrc, int n, int E) {
    int idx = blockIdx.x * 256 + threadIdx.x;
    if (idx < n) {
        int base = rowptr[idx] + blocksums[blockIdx.x];
        rowptr[idx] = base;
        int dout = 0;
        #pragma unroll
        for (int k = 0; k < CHUNKS; ++k) {
            cursorC[(size_t)k * n + idx] = base;
            base += cntC_in[(size_t)k * n + idx];
            dout += cntC_out[(size_t)k * n + idx];
        }
        float di = (float)cnt_tot_in[idx];
        float ns = rsqrtf(fmaxf((float)dout, 1.0f));
        norm_src[idx] = ns;
        norm_dst[idx] = rsqrtf(fmaxf(di, 1.0f));
        vsrc[idx] = di * ns;
    }
    if (idx == 0) rowptr[n] = E;
}

// fill CSR columns: LDS cursors per (range, chunk) block — no global atomics
__global__ void k_fillv2(const int* __restrict__ src, const int* __restrict__ dst,
                         const int* __restrict__ cursorC, int* __restrict__ colsrc,
                         int nr, int n, int E) {
    __shared__ int cur[RANGE];
    int bid = blockIdx.x;
    int r = bid / CHUNKS, c = bid - r * CHUNKS;
    int lo = r * RANGE;
    int hi = min(n - lo, RANGE);
    for (int i = threadIdx.x; i < hi; i += 256)
        cur[i] = cursorC[(size_t)c * n + lo + i];
    __syncthreads();

    int e0 = (E / CHUNKS) * c;
    int e1 = (c == CHUNKS - 1) ? E : e0 + E / CHUNKS;
    for (int e = e0 + threadIdx.x; e < e1; e += 256) {
        int d = dst[e] - lo;
        if ((unsigned)d < (unsigned)hi) {
            int pos = atomicAdd(&cur[d], 1);   // LDS atomic
            colsrc[pos] = src[e];              // plain scattered store
        }
    }
}

// ============ layer 0: wave-per-node gather + rank-1 dense ============
__global__ void k_layer0(const int* __restrict__ rowptr, const int* __restrict__ colsrc,
                         const float* __restrict__ vsrc, const float* __restrict__ norm_dst,
                         const float* __restrict__ norm_src,
                         const float* __restrict__ W0, const float* __restrict__ b0,
                         bf16_t* __restrict__ out, int n) {
    int wave = threadIdx.x >> 6, lane = threadIdx.x & 63;
    int i = blockIdx.x * 4 + wave;
    if (i >= n) return;
    int p0 = rowptr[i], pe = rowptr[i + 1];
    float s = 0.0f;
    for (int p = p0 + lane; p < pe; p += 64) s += vsrc[colsrc[p]];
    #pragma unroll
    for (int off = 32; off > 0; off >>= 1) s += __shfl_xor(s, off);
    float v = fmaxf(s * norm_dst[i] * W0[lane] + b0[lane], 0.0f) * norm_src[i];
    out[(size_t)i * 64 + lane] = f2bf(v);
}

// ============ pure CSR row-gather: agg[i][:] = (sum_e hin[col]) * norm_dst[i] ============
__global__ void k_gather(const int* __restrict__ rowptr, const int* __restrict__ colsrc,
                         const bf16_t* __restrict__ hin, const float* __restrict__ norm_dst,
                         bf16_t* __restrict__ aggout, int n) {
    int wave = threadIdx.x >> 6, j = threadIdx.x & 63;
    int i = blockIdx.x * 4 + wave;
    if (i >= n) return;
    int p0 = rowptr[i], deg = rowptr[i + 1] - p0;
    float a0 = 0.0f, a1 = 0.0f, a2 = 0.0f, a3 = 0.0f;
    float a4 = 0.0f, a5 = 0.0f, a6 = 0.0f, a7 = 0.0f;
    for (int cb = 0; cb < deg; cb += 64) {
        int m = min(64, deg - cb);
        int col = (j < m) ? colsrc[p0 + cb + j] : 0;  // one lane-parallel VMEM
        int e = 0;
        for (; e + 8 <= m; e += 8) {
            int c0 = __shfl(col, e + 0), c1 = __shfl(col, e + 1);
            int c2 = __shfl(col, e + 2), c3 = __shfl(col, e + 3);
            int c4 = __shfl(col, e + 4), c5 = __shfl(col, e + 5);
            int c6 = __shfl(col, e + 6), c7 = __shfl(col, e + 7);
            a0 += bf2f(hin[(size_t)c0 * 64 + j]);
            a1 += bf2f(hin[(size_t)c1 * 64 + j]);
            a2 += bf2f(hin[(size_t)c2 * 64 + j]);
            a3 += bf2f(hin[(size_t)c3 * 64 + j]);
            a4 += bf2f(hin[(size_t)c4 * 64 + j]);
            a5 += bf2f(hin[(size_t)c5 * 64 + j]);
            a6 += bf2f(hin[(size_t)c6 * 64 + j]);
            a7 += bf2f(hin[(size_t)c7 * 64 + j]);
        }
        for (; e < m; ++e) {
            int c = __shfl(col, e);
            a0 += bf2f(hin[(size_t)c * 64 + j]);
        }
    }
    float s = (((a0 + a1) + (a2 + a3)) + ((a4 + a5) + (a6 + a7))) * norm_dst[i];
    aggout[(size_t)i * 64 + j] = f2bf(s);
}

// ============ MFMA dense: out = relu(agg @ W + b) [*norm_src | .Wr] ============
template <int FUSE_DOT>
__global__ void k_gemm(const bf16_t* __restrict__ agg, const float* __restrict__ W,
                       const float* __restrict__ b, const float* __restrict__ norm_src,
                       const float* __restrict__ Wr,
                       bf16_t* __restrict__ hout, float* __restrict__ rout, int n) {
    __shared__ bf16_t Wbf[64 * 64];
    __shared__ float bs[64];
    int tid = threadIdx.x;
    #pragma unroll
    for (int it = 0; it < 16; ++it) {
        int idx = tid + it * 256;
        Wbf[idx] = f2bf(W[idx]);
    }
    if (tid < 64) bs[tid] = b[tid];
    __syncthreads();

    int wave = tid >> 6, lane = tid & 63;
    int quad = lane >> 4, l16 = lane & 15;

    // B fragments: W[k][f], f = t*16+l16, k = c*32 + quad*8 + jj
    s8v bfrag[4][2];
    #pragma unroll
    for (int t = 0; t < 4; ++t)
        #pragma unroll
        for (int c = 0; c < 2; ++c)
            #pragma unroll
            for (int jj = 0; jj < 8; ++jj)
                bfrag[t][c][jj] = (short)Wbf[(c * 32 + quad * 8 + jj) * 64 + t * 16 + l16];

    int m0 = (blockIdx.x * 4 + wave) * 16;
    if (m0 >= n) return;

    int arow_i = m0 + l16; if (arow_i >= n) arow_i = n - 1;
    const s8v* arow = (const s8v*)(agg + (size_t)arow_i * 64);
    s8v a0 = arow[quad];      // k in [0,32)
    s8v a1 = arow[quad + 4];  // k in [32,64)

    f4v acc[4];
    #pragma unroll
    for (int t = 0; t < 4; ++t) { acc[t][0] = 0.f; acc[t][1] = 0.f; acc[t][2] = 0.f; acc[t][3] = 0.f; }
    #pragma unroll
    for (int t = 0; t < 4; ++t) {
        acc[t] = __builtin_amdgcn_mfma_f32_16x16x32_bf16(a0, bfrag[t][0], acc[t], 0, 0, 0);
        acc[t] = __builtin_amdgcn_mfma_f32_16x16x32_bf16(a1, bfrag[t][1], acc[t], 0, 0, 0);
    }

    if (FUSE_DOT) {
        float p0 = 0.f, p1 = 0.f, p2 = 0.f, p3 = 0.f;
        #pragma unroll
        for (int t = 0; t < 4; ++t) {
            float wr = Wr[t * 16 + l16];
            float bias = bs[t * 16 + l16];
            p0 = fmaf(fmaxf(acc[t][0] + bias, 0.f), wr, p0);
            p1 = fmaf(fmaxf(acc[t][1] + bias, 0.f), wr, p1);
            p2 = fmaf(fmaxf(acc[t][2] + bias, 0.f), wr, p2);
            p3 = fmaf(fmaxf(acc[t][3] + bias, 0.f), wr, p3);
        }
        float pr[4] = {p0, p1, p2, p3};
        #pragma unroll
        for (int r = 0; r < 4; ++r) {
            float v = pr[r];
            v += __shfl_xor(v, 1); v += __shfl_xor(v, 2);
            v += __shfl_xor(v, 4); v += __shfl_xor(v, 8);
            int i = m0 + quad * 4 + r;
            if (l16 == 0 && i < n) rout[i] = v;
        }
    } else {
        float ns[4];
        #pragma unroll
        for (int r = 0; r < 4; ++r) {
            int i = m0 + quad * 4 + r;
            ns[r] = norm_src[i < n ? i : n - 1];
        }
        #pragma unroll
        for (int t = 0; t < 4; ++t) {
            float bias = bs[t * 16 + l16];
            #pragma unroll
            for (int r = 0; r < 4; ++r) {
                int i = m0 + quad * 4 + r;
                if (i < n) {
                    float v = fmaxf(acc[t][r] + bias, 0.f) * ns[r];
                    hout[(size_t)i * 64 + t * 16 + l16] = f2bf(v);
                }
            }
        }
    }
}

// ============ readout ============
__global__ void k_bounds(const int* __restrict__ n2g, int* __restrict__ bnd, int n) {
    int g = threadIdx.x;
    if (g > NGRAPHS) return;
    int lo = 0, hi = n;
    while (lo < hi) {
        int mid = (lo + hi) >> 1;
        if (n2g[mid] < g) lo = mid + 1; else hi = mid;
    }
    bnd[g] = lo;
}

__global__ void k_mean(const float* __restrict__ r, const int* __restrict__ bnd,
                       const float* __restrict__ br, float* __restrict__ out) {
    __shared__ float ssum[4];
    int g = blockIdx.x;
    int lo = bnd[g], hi = bnd[g + 1];
    int tid = threadIdx.x;
    float s = 0.0f;
    for (int i = lo + tid; i < hi; i += 256) s += r[i];
    #pragma unroll
    for (int off = 32; off > 0; off >>= 1) s += __shfl_down(s, off);
    int wave = tid >> 6;
    if ((tid & 63) == 0) ssum[wave] = s;
    __syncthreads();
    if (tid == 0) {
        float S = ssum[0] + ssum[1] + ssum[2] + ssum[3];
        out[g] = S / fmaxf((float)(hi - lo), 1.0f) + br[0];
    }
}

extern "C" void kernel_launch(void* const* d_in, const int* in_sizes, int n_in,
                              void* d_out, int out_size, void* d_ws, size_t ws_size,
                              hipStream_t stream) {
    const int* src = (const int*)d_in[0];
    const int* dst = (const int*)d_in[1];
    const int* n2g = (const int*)d_in[2];
    const float* W0 = (const float*)d_in[3];
    const float* b0 = (const float*)d_in[4];
    const float* W1 = (const float*)d_in[5];
    const float* b1 = (const float*)d_in[6];
    const float* W2 = (const float*)d_in[7];
    const float* b2 = (const float*)d_in[8];
    const float* Wr = (const float*)d_in[9];
    const float* br = (const float*)d_in[10];
    float* out = (float*)d_out;

    int E = in_sizes[0];
    int n = in_sizes[2];
    int nb = (n + 255) / 256;
    int nr = (n + RANGE - 1) / RANGE;

    // aligned workspace carve-up
    char* base = (char*)d_ws;
    size_t off = 0;
    auto alloc = [&](size_t bytes) -> void* {
        off = (off + 255) & ~(size_t)255;
        void* p = base + off;
        off += bytes;
        return p;
    };
    int* cntC_in = (int*)alloc((size_t)CHUNKS * n * sizeof(int));
    int* cntC_out = (int*)alloc((size_t)CHUNKS * n * sizeof(int));
    int* cursorC = (int*)alloc((size_t)CHUNKS * n * sizeof(int));
    int* cnt_tot_in = (int*)alloc((size_t)n * sizeof(int));
    int* rowptr = (int*)alloc((size_t)(n + 1) * sizeof(int));
    int* blocksums = (int*)alloc(256 * sizeof(int));
    int* bnd = (int*)alloc(65 * sizeof(int));
    int* colsrc = (int*)alloc((size_t)E * sizeof(int));
    float* norm_src = (float*)alloc((size_t)n * sizeof(float));
    float* norm_dst = (float*)alloc((size_t)n * sizeof(float));
    float* vsrc = (float*)alloc((size_t)n * sizeof(float));
    float* rbuf = (float*)alloc((size_t)n * sizeof(float));
    bf16_t* hA = (bf16_t*)alloc((size_t)n * 64 * sizeof(bf16_t));
    bf16_t* hB = (bf16_t*)alloc((size_t)n * 64 * sizeof(bf16_t));
    bf16_t* aggb = (bf16_t*)alloc((size_t)n * 64 * sizeof(bf16_t));

    // CSR build — no memset, no global atomics
    k_hist<<<2 * nr * CHUNKS, 256, 0, stream>>>(src, dst, cntC_in, cntC_out, nr, n, E);
    k_scan1<<<nb, 256, 0, stream>>>(cntC_in, cnt_tot_in, rowptr, blocksums, n);
    k_scan2<<<1, 256, 0, stream>>>(blocksums, nb);
    k_scan3<<<nb, 256, 0, stream>>>(rowptr, blocksums, cntC_in, cntC_out, cnt_tot_in,
                                    cursorC, norm_src, norm_dst, vsrc, n, E);
    k_fillv2<<<nr * CHUNKS, 256, 0, stream>>>(src, dst, cursorC, colsrc, nr, n, E);
    k_bounds<<<1, 128, 0, stream>>>(n2g, bnd, n);

    // layer 0
    k_layer0<<<(n + 3) / 4, 256, 0, stream>>>(rowptr, colsrc, vsrc, norm_dst, norm_src,
                                              W0, b0, hA, n);

    // layers 1,2: gather + MFMA dense
    int ggather = (n + 3) / 4;
    int ggemm = ((n + 15) / 16 + 3) / 4;
    k_gather<<<ggather, 256, 0, stream>>>(rowptr, colsrc, hA, norm_dst, aggb, n);
    k_gemm<0><<<ggemm, 256, 0, stream>>>(aggb, W1, b1, norm_src, nullptr, hB, nullptr, n);
    k_gather<<<ggather, 256, 0, stream>>>(rowptr, colsrc, hB, norm_dst, aggb, n);
    k_gemm<1><<<ggemm, 256, 0, stream>>>(aggb, W2, b2, nullptr, Wr, nullptr, rbuf, n);

    // readout
    k_mean<<<NGRAPHS, 256, 0, stream>>>(rbuf, bnd, br, out);
}

// Round 11
// 230.451 us; speedup vs baseline: 1.3390x; 1.3390x over previous
//
#include <hip/hip_runtime.h>
#include <hip/hip_bf16.h>

#define NGRAPHS 64
#define RANGE 8192
#define RSHIFT 13
#define CHUNKS 16

typedef unsigned short u16;
typedef unsigned int u32;
typedef unsigned short bf16_t;
using s8v = __attribute__((ext_vector_type(8))) short;   // 8 bf16 (4 VGPRs)
using f4v = __attribute__((ext_vector_type(4))) float;   // MFMA accumulator

__device__ inline float bf2f(bf16_t u) { return __uint_as_float(((unsigned)u) << 16); }
__device__ inline bf16_t f2bf(float f) {
    unsigned x = __float_as_uint(f);
    return (bf16_t)((x + 0x7fffu + ((x >> 16) & 1u)) >> 16);  // RNE
}

// ============ CSR build: bucket partition, per-edge atomics are LDS-only ============

// count bucket sizes (dst-range and src-range)
__global__ void k_p0(const int* __restrict__ src, const int* __restrict__ dst,
                     int* __restrict__ dsz, int* __restrict__ ssz, int nr, int E) {
    __shared__ int ld[16], ls[16];
    int tid = threadIdx.x;
    if (tid < 16) { ld[tid] = 0; ls[tid] = 0; }
    __syncthreads();
    int e4 = (blockIdx.x * 256 + tid) * 4;
    if (e4 + 4 <= E) {
        int4 d = *(const int4*)&dst[e4];
        int4 s = *(const int4*)&src[e4];
        atomicAdd(&ld[d.x >> RSHIFT], 1); atomicAdd(&ld[d.y >> RSHIFT], 1);
        atomicAdd(&ld[d.z >> RSHIFT], 1); atomicAdd(&ld[d.w >> RSHIFT], 1);
        atomicAdd(&ls[s.x >> RSHIFT], 1); atomicAdd(&ls[s.y >> RSHIFT], 1);
        atomicAdd(&ls[s.z >> RSHIFT], 1); atomicAdd(&ls[s.w >> RSHIFT], 1);
    } else {
        for (int e = e4; e < E; ++e) {
            atomicAdd(&ld[dst[e] >> RSHIFT], 1);
            atomicAdd(&ls[src[e] >> RSHIFT], 1);
        }
    }
    __syncthreads();
    if (tid < nr) {
        if (ld[tid]) atomicAdd(&dsz[tid], ld[tid]);
        if (ls[tid]) atomicAdd(&ssz[tid], ls[tid]);
    }
}

__global__ void k_pscan(const int* __restrict__ dsz, const int* __restrict__ ssz,
                        int* __restrict__ dbase, int* __restrict__ sbase,
                        int* __restrict__ dcur, int* __restrict__ scur, int nr) {
    if (threadIdx.x == 0) {
        int a = 0;
        for (int r = 0; r < nr; ++r) { dbase[r] = a; dcur[r] = a; a += dsz[r]; }
        dbase[nr] = a;
        a = 0;
        for (int r = 0; r < nr; ++r) { sbase[r] = a; scur[r] = a; a += ssz[r]; }
        sbase[nr] = a;
    }
}

// partition: ebuf = (src<<16|dst) grouped by dst-range; sbuf = src grouped by src-range
__global__ void k_p1(const int* __restrict__ src, const int* __restrict__ dst,
                     int* __restrict__ dcur, int* __restrict__ scur,
                     u32* __restrict__ ebuf, u16* __restrict__ sbuf, int nr, int E) {
    __shared__ int ldc[16], lsc[16], gdb[16], gsb[16];
    int tid = threadIdx.x;
    if (tid < 16) { ldc[tid] = 0; lsc[tid] = 0; }
    __syncthreads();
    int e4 = (blockIdx.x * 256 + tid) * 4;
    int s[4], d[4], pd[4], ps[4];
    int cnt = 0;
    if (e4 + 4 <= E) {
        int4 dv = *(const int4*)&dst[e4];
        int4 sv = *(const int4*)&src[e4];
        s[0] = sv.x; s[1] = sv.y; s[2] = sv.z; s[3] = sv.w;
        d[0] = dv.x; d[1] = dv.y; d[2] = dv.z; d[3] = dv.w;
        cnt = 4;
    } else {
        for (int e = e4; e < E; ++e) { s[cnt] = src[e]; d[cnt] = dst[e]; ++cnt; }
    }
    for (int i = 0; i < cnt; ++i) {
        pd[i] = atomicAdd(&ldc[d[i] >> RSHIFT], 1);   // LDS local rank
        ps[i] = atomicAdd(&lsc[s[i] >> RSHIFT], 1);
    }
    __syncthreads();
    if (tid < nr) {
        gdb[tid] = atomicAdd(&dcur[tid], ldc[tid]);   // 14 global atomics per block total
        gsb[tid] = atomicAdd(&scur[tid], lsc[tid]);
    }
    __syncthreads();
    for (int i = 0; i < cnt; ++i) {
        int db = d[i] >> RSHIFT, sb = s[i] >> RSHIFT;
        ebuf[gdb[db] + pd[i]] = ((u32)s[i] << 16) | (u32)d[i];
        sbuf[gsb[sb] + ps[i]] = (u16)s[i];
    }
}

// histogram each (type, range, chunk): no filtering waste, edges guaranteed in-range
__global__ void k_hist(const u32* __restrict__ ebuf, const u16* __restrict__ sbuf,
                       const int* __restrict__ dbase, const int* __restrict__ sbase,
                       int* __restrict__ cntC_in, int* __restrict__ cntC_out,
                       int nr, int n) {
    __shared__ int hist[RANGE];
    int tid = threadIdx.x, bid = blockIdx.x;
    int type = bid / (nr * CHUNKS);
    int rem = bid - type * nr * CHUNKS;
    int r = rem / CHUNKS, c = rem - r * CHUNKS;
    for (int i = tid; i < RANGE; i += 256) hist[i] = 0;
    __syncthreads();
    int lo = r * RANGE;
    int seg0 = type ? sbase[r] : dbase[r];
    int seg1 = type ? sbase[r + 1] : dbase[r + 1];
    int sz = seg1 - seg0;
    int ce0 = seg0 + (int)((long long)sz * c / CHUNKS);
    int ce1 = seg0 + (int)((long long)sz * (c + 1) / CHUNKS);
    int e = ce0 + tid;
    if (type == 0) {
        for (; e + 768 < ce1; e += 1024) {
            int k0 = ebuf[e] & 0xFFFF, k1 = ebuf[e + 256] & 0xFFFF;
            int k2 = ebuf[e + 512] & 0xFFFF, k3 = ebuf[e + 768] & 0xFFFF;
            atomicAdd(&hist[k0 - lo], 1); atomicAdd(&hist[k1 - lo], 1);
            atomicAdd(&hist[k2 - lo], 1); atomicAdd(&hist[k3 - lo], 1);
        }
        for (; e < ce1; e += 256) atomicAdd(&hist[(ebuf[e] & 0xFFFF) - lo], 1);
    } else {
        for (; e + 768 < ce1; e += 1024) {
            int k0 = sbuf[e], k1 = sbuf[e + 256], k2 = sbuf[e + 512], k3 = sbuf[e + 768];
            atomicAdd(&hist[k0 - lo], 1); atomicAdd(&hist[k1 - lo], 1);
            atomicAdd(&hist[k2 - lo], 1); atomicAdd(&hist[k3 - lo], 1);
        }
        for (; e < ce1; e += 256) atomicAdd(&hist[(int)sbuf[e] - lo], 1);
    }
    __syncthreads();
    int hi = min(n - lo, RANGE);
    int* __restrict__ outb = (type ? cntC_out : cntC_in) + (size_t)c * n + lo;
    for (int i = tid; i < hi; i += 256) outb[i] = hist[i];   // plain store, owned once
}

__device__ inline int block_excl_scan(int v, int tid, int* wavesums, int* block_total) {
    int lane = tid & 63, wave = tid >> 6;
    int incl = v;
    #pragma unroll
    for (int off = 1; off < 64; off <<= 1) {
        int t = __shfl_up(incl, off);
        if (lane >= off) incl += t;
    }
    if (lane == 63) wavesums[wave] = incl;
    __syncthreads();
    int woff = 0;
    #pragma unroll
    for (int w = 0; w < 4; ++w) if (w < wave) woff += wavesums[w];
    *block_total = wavesums[0] + wavesums[1] + wavesums[2] + wavesums[3];
    return incl + woff - v;
}

__global__ void k_scan1(const int* __restrict__ cntC_in, int* __restrict__ cnt_tot_in,
                        int* __restrict__ rowptr, int* __restrict__ blocksums, int n) {
    __shared__ int wavesums[4];
    int tid = threadIdx.x;
    int idx = blockIdx.x * 256 + tid;
    int v = 0;
    if (idx < n) {
        #pragma unroll
        for (int k = 0; k < CHUNKS; ++k) v += cntC_in[(size_t)k * n + idx];
        cnt_tot_in[idx] = v;
    }
    int total;
    int excl = block_excl_scan(v, tid, wavesums, &total);
    if (idx < n) rowptr[idx] = excl;
    if (tid == 0) blocksums[blockIdx.x] = total;
}

__global__ void k_scan2(int* __restrict__ blocksums, int nb) {
    __shared__ int wavesums[4];
    int tid = threadIdx.x;
    int v = (tid < nb) ? blocksums[tid] : 0;
    int total;
    int excl = block_excl_scan(v, tid, wavesums, &total);
    if (tid < nb) blocksums[tid] = excl;
}

__global__ void k_scan3(int* __restrict__ rowptr, const int* __restrict__ blocksums,
                        const int* __restrict__ cntC_in, const int* __restrict__ cntC_out,
                        const int* __restrict__ cnt_tot_in,
                        int* __restrict__ cursorC,
                        float* __restrict__ norm_src, float* __restrict__ norm_dst,
                        float* __restrict__ vsrc, int n, int E) {
    int idx = blockIdx.x * 256 + threadIdx.x;
    if (idx < n) {
        int base = rowptr[idx] + blocksums[blockIdx.x];
        rowptr[idx] = base;
        int dout = 0;
        #pragma unroll
        for (int k = 0; k < CHUNKS; ++k) {
            cursorC[(size_t)k * n + idx] = base;
            base += cntC_in[(size_t)k * n + idx];
            dout += cntC_out[(size_t)k * n + idx];
        }
        float di = (float)cnt_tot_in[idx];
        float ns = rsqrtf(fmaxf((float)dout, 1.0f));
        norm_src[idx] = ns;
        norm_dst[idx] = rsqrtf(fmaxf(di, 1.0f));
        vsrc[idx] = di * ns;
    }
    if (idx == 0) rowptr[n] = E;
}

// fill: each block handles its OWN bucket chunk only; LDS cursors
__global__ void k_fillv2(const u32* __restrict__ ebuf, const int* __restrict__ dbase,
                         const int* __restrict__ cursorC, u16* __restrict__ colsrc,
                         int nr, int n) {
    __shared__ int cur[RANGE];
    int tid = threadIdx.x, bid = blockIdx.x;
    int r = bid / CHUNKS, c = bid - r * CHUNKS;
    int lo = r * RANGE, hi = min(n - lo, RANGE);
    for (int i = tid; i < hi; i += 256) cur[i] = cursorC[(size_t)c * n + lo + i];
    __syncthreads();
    int seg0 = dbase[r], seg1 = dbase[r + 1];
    int sz = seg1 - seg0;
    int ce0 = seg0 + (int)((long long)sz * c / CHUNKS);
    int ce1 = seg0 + (int)((long long)sz * (c + 1) / CHUNKS);
    int e = ce0 + tid;
    for (; e + 768 < ce1; e += 1024) {
        u32 v0 = ebuf[e], v1 = ebuf[e + 256], v2 = ebuf[e + 512], v3 = ebuf[e + 768];
        colsrc[atomicAdd(&cur[(v0 & 0xFFFF) - lo], 1)] = (u16)(v0 >> 16);
        colsrc[atomicAdd(&cur[(v1 & 0xFFFF) - lo], 1)] = (u16)(v1 >> 16);
        colsrc[atomicAdd(&cur[(v2 & 0xFFFF) - lo], 1)] = (u16)(v2 >> 16);
        colsrc[atomicAdd(&cur[(v3 & 0xFFFF) - lo], 1)] = (u16)(v3 >> 16);
    }
    for (; e < ce1; e += 256) {
        u32 v = ebuf[e];
        colsrc[atomicAdd(&cur[(v & 0xFFFF) - lo], 1)] = (u16)(v >> 16);
    }
}

// ============ layer 0: wave-per-node gather + rank-1 dense ============
__global__ void k_layer0(const int* __restrict__ rowptr, const u16* __restrict__ colsrc,
                         const float* __restrict__ vsrc, const float* __restrict__ norm_dst,
                         const float* __restrict__ norm_src,
                         const float* __restrict__ W0, const float* __restrict__ b0,
                         bf16_t* __restrict__ out, int n) {
    int wave = threadIdx.x >> 6, lane = threadIdx.x & 63;
    int i = blockIdx.x * 4 + wave;
    if (i >= n) return;
    int p0 = rowptr[i], pe = rowptr[i + 1];
    float s = 0.0f;
    for (int p = p0 + lane; p < pe; p += 64) s += vsrc[colsrc[p]];
    #pragma unroll
    for (int off = 32; off > 0; off >>= 1) s += __shfl_xor(s, off);
    float v = fmaxf(s * norm_dst[i] * W0[lane] + b0[lane], 0.0f) * norm_src[i];
    out[(size_t)i * 64 + lane] = f2bf(v);
}

// ============ pure CSR row-gather ============
__global__ void k_gather(const int* __restrict__ rowptr, const u16* __restrict__ colsrc,
                         const bf16_t* __restrict__ hin, const float* __restrict__ norm_dst,
                         bf16_t* __restrict__ aggout, int n) {
    int wave = threadIdx.x >> 6, j = threadIdx.x & 63;
    int i = blockIdx.x * 4 + wave;
    if (i >= n) return;
    int p0 = rowptr[i], deg = rowptr[i + 1] - p0;
    float a0 = 0.0f, a1 = 0.0f, a2 = 0.0f, a3 = 0.0f;
    float a4 = 0.0f, a5 = 0.0f, a6 = 0.0f, a7 = 0.0f;
    for (int cb = 0; cb < deg; cb += 64) {
        int m = min(64, deg - cb);
        int col = (j < m) ? (int)colsrc[p0 + cb + j] : 0;
        int e = 0;
        for (; e + 8 <= m; e += 8) {
            int c0 = __shfl(col, e + 0), c1 = __shfl(col, e + 1);
            int c2 = __shfl(col, e + 2), c3 = __shfl(col, e + 3);
            int c4 = __shfl(col, e + 4), c5 = __shfl(col, e + 5);
            int c6 = __shfl(col, e + 6), c7 = __shfl(col, e + 7);
            a0 += bf2f(hin[(size_t)c0 * 64 + j]);
            a1 += bf2f(hin[(size_t)c1 * 64 + j]);
            a2 += bf2f(hin[(size_t)c2 * 64 + j]);
            a3 += bf2f(hin[(size_t)c3 * 64 + j]);
            a4 += bf2f(hin[(size_t)c4 * 64 + j]);
            a5 += bf2f(hin[(size_t)c5 * 64 + j]);
            a6 += bf2f(hin[(size_t)c6 * 64 + j]);
            a7 += bf2f(hin[(size_t)c7 * 64 + j]);
        }
        for (; e < m; ++e) {
            int c = __shfl(col, e);
            a0 += bf2f(hin[(size_t)c * 64 + j]);
        }
    }
    float s = (((a0 + a1) + (a2 + a3)) + ((a4 + a5) + (a6 + a7))) * norm_dst[i];
    aggout[(size_t)i * 64 + j] = f2bf(s);
}

// ============ MFMA dense ============
template <int FUSE_DOT>
__global__ void k_gemm(const bf16_t* __restrict__ agg, const float* __restrict__ W,
                       const float* __restrict__ b, const float* __restrict__ norm_src,
                       const float* __restrict__ Wr,
                       bf16_t* __restrict__ hout, float* __restrict__ rout, int n) {
    __shared__ bf16_t Wbf[64 * 64];
    __shared__ float bs[64];
    int tid = threadIdx.x;
    #pragma unroll
    for (int it = 0; it < 16; ++it) {
        int idx = tid + it * 256;
        Wbf[idx] = f2bf(W[idx]);
    }
    if (tid < 64) bs[tid] = b[tid];
    __syncthreads();

    int wave = tid >> 6, lane = tid & 63;
    int quad = lane >> 4, l16 = lane & 15;

    s8v bfrag[4][2];
    #pragma unroll
    for (int t = 0; t < 4; ++t)
        #pragma unroll
        for (int c = 0; c < 2; ++c)
            #pragma unroll
            for (int jj = 0; jj < 8; ++jj)
                bfrag[t][c][jj] = (short)Wbf[(c * 32 + quad * 8 + jj) * 64 + t * 16 + l16];

    int m0 = (blockIdx.x * 4 + wave) * 16;
    if (m0 >= n) return;

    int arow_i = m0 + l16; if (arow_i >= n) arow_i = n - 1;
    const s8v* arow = (const s8v*)(agg + (size_t)arow_i * 64);
    s8v a0 = arow[quad];
    s8v a1 = arow[quad + 4];

    f4v acc[4];
    #pragma unroll
    for (int t = 0; t < 4; ++t) { acc[t][0] = 0.f; acc[t][1] = 0.f; acc[t][2] = 0.f; acc[t][3] = 0.f; }
    #pragma unroll
    for (int t = 0; t < 4; ++t) {
        acc[t] = __builtin_amdgcn_mfma_f32_16x16x32_bf16(a0, bfrag[t][0], acc[t], 0, 0, 0);
        acc[t] = __builtin_amdgcn_mfma_f32_16x16x32_bf16(a1, bfrag[t][1], acc[t], 0, 0, 0);
    }

    if (FUSE_DOT) {
        float p0 = 0.f, p1 = 0.f, p2 = 0.f, p3 = 0.f;
        #pragma unroll
        for (int t = 0; t < 4; ++t) {
            float wr = Wr[t * 16 + l16];
            float bias = bs[t * 16 + l16];
            p0 = fmaf(fmaxf(acc[t][0] + bias, 0.f), wr, p0);
            p1 = fmaf(fmaxf(acc[t][1] + bias, 0.f), wr, p1);
            p2 = fmaf(fmaxf(acc[t][2] + bias, 0.f), wr, p2);
            p3 = fmaf(fmaxf(acc[t][3] + bias, 0.f), wr, p3);
        }
        float pr[4] = {p0, p1, p2, p3};
        #pragma unroll
        for (int r = 0; r < 4; ++r) {
            float v = pr[r];
            v += __shfl_xor(v, 1); v += __shfl_xor(v, 2);
            v += __shfl_xor(v, 4); v += __shfl_xor(v, 8);
            int i = m0 + quad * 4 + r;
            if (l16 == 0 && i < n) rout[i] = v;
        }
    } else {
        float ns[4];
        #pragma unroll
        for (int r = 0; r < 4; ++r) {
            int i = m0 + quad * 4 + r;
            ns[r] = norm_src[i < n ? i : n - 1];
        }
        #pragma unroll
        for (int t = 0; t < 4; ++t) {
            float bias = bs[t * 16 + l16];
            #pragma unroll
            for (int r = 0; r < 4; ++r) {
                int i = m0 + quad * 4 + r;
                if (i < n) {
                    float v = fmaxf(acc[t][r] + bias, 0.f) * ns[r];
                    hout[(size_t)i * 64 + t * 16 + l16] = f2bf(v);
                }
            }
        }
    }
}

// ============ readout ============
__global__ void k_bounds(const int* __restrict__ n2g, int* __restrict__ bnd, int n) {
    int g = threadIdx.x;
    if (g > NGRAPHS) return;
    int lo = 0, hi = n;
    while (lo < hi) {
        int mid = (lo + hi) >> 1;
        if (n2g[mid] < g) lo = mid + 1; else hi = mid;
    }
    bnd[g] = lo;
}

__global__ void k_mean(const float* __restrict__ r, const int* __restrict__ bnd,
                       const float* __restrict__ br, float* __restrict__ out) {
    __shared__ float ssum[4];
    int g = blockIdx.x;
    int lo = bnd[g], hi = bnd[g + 1];
    int tid = threadIdx.x;
    float s = 0.0f;
    for (int i = lo + tid; i < hi; i += 256) s += r[i];
    #pragma unroll
    for (int off = 32; off > 0; off >>= 1) s += __shfl_down(s, off);
    int wave = tid >> 6;
    if ((tid & 63) == 0) ssum[wave] = s;
    __syncthreads();
    if (tid == 0) {
        float S = ssum[0] + ssum[1] + ssum[2] + ssum[3];
        out[g] = S / fmaxf((float)(hi - lo), 1.0f) + br[0];
    }
}

extern "C" void kernel_launch(void* const* d_in, const int* in_sizes, int n_in,
                              void* d_out, int out_size, void* d_ws, size_t ws_size,
                              hipStream_t stream) {
    const int* src = (const int*)d_in[0];
    const int* dst = (const int*)d_in[1];
    const int* n2g = (const int*)d_in[2];
    const float* W0 = (const float*)d_in[3];
    const float* b0 = (const float*)d_in[4];
    const float* W1 = (const float*)d_in[5];
    const float* b1 = (const float*)d_in[6];
    const float* W2 = (const float*)d_in[7];
    const float* b2 = (const float*)d_in[8];
    const float* Wr = (const float*)d_in[9];
    const float* br = (const float*)d_in[10];
    float* out = (float*)d_out;

    int E = in_sizes[0];
    int n = in_sizes[2];          // 50000 (< 65536: u16 packing valid)
    int nb = (n + 255) / 256;     // 196
    int nr = (n + RANGE - 1) / RANGE;  // 7

    char* base = (char*)d_ws;
    size_t off = 0;
    auto alloc = [&](size_t bytes) -> void* {
        off = (off + 255) & ~(size_t)255;
        void* p = base + off;
        off += bytes;
        return p;
    };
    int* meta = (int*)alloc(96 * sizeof(int));
    int* dsz = meta;          // 16
    int* ssz = meta + 16;     // 16
    int* dbase = meta + 32;   // 16
    int* sbase = meta + 48;   // 16
    int* dcur = meta + 64;    // 16
    int* scur = meta + 80;    // 16
    u32* ebuf = (u32*)alloc((size_t)E * sizeof(u32));
    u16* sbuf = (u16*)alloc((size_t)E * sizeof(u16));
    int* cntC_in = (int*)alloc((size_t)CHUNKS * n * sizeof(int));
    int* cntC_out = (int*)alloc((size_t)CHUNKS * n * sizeof(int));
    int* cursorC = (int*)alloc((size_t)CHUNKS * n * sizeof(int));
    int* cnt_tot_in = (int*)alloc((size_t)n * sizeof(int));
    int* rowptr = (int*)alloc((size_t)(n + 1) * sizeof(int));
    int* blocksums = (int*)alloc(256 * sizeof(int));
    int* bnd = (int*)alloc(65 * sizeof(int));
    u16* colsrc = (u16*)alloc((size_t)E * sizeof(u16));
    float* norm_src = (float*)alloc((size_t)n * sizeof(float));
    float* norm_dst = (float*)alloc((size_t)n * sizeof(float));
    float* vsrc = (float*)alloc((size_t)n * sizeof(float));
    float* rbuf = (float*)alloc((size_t)n * sizeof(float));
    bf16_t* hA = (bf16_t*)alloc((size_t)n * 64 * sizeof(bf16_t));
    bf16_t* aggX = (bf16_t*)alloc((size_t)n * 64 * sizeof(bf16_t));

    hipMemsetAsync(meta, 0, 32 * sizeof(int), stream);  // dsz + ssz only

    int gP = (E + 1023) / 1024;
    k_p0<<<gP, 256, 0, stream>>>(src, dst, dsz, ssz, nr, E);
    k_pscan<<<1, 64, 0, stream>>>(dsz, ssz, dbase, sbase, dcur, scur, nr);
    k_p1<<<gP, 256, 0, stream>>>(src, dst, dcur, scur, ebuf, sbuf, nr, E);
    k_hist<<<2 * nr * CHUNKS, 256, 0, stream>>>(ebuf, sbuf, dbase, sbase,
                                                cntC_in, cntC_out, nr, n);
    k_scan1<<<nb, 256, 0, stream>>>(cntC_in, cnt_tot_in, rowptr, blocksums, n);
    k_scan2<<<1, 256, 0, stream>>>(blocksums, nb);
    k_scan3<<<nb, 256, 0, stream>>>(rowptr, blocksums, cntC_in, cntC_out, cnt_tot_in,
                                    cursorC, norm_src, norm_dst, vsrc, n, E);
    k_fillv2<<<nr * CHUNKS, 256, 0, stream>>>(ebuf, dbase, cursorC, colsrc, nr, n);
    k_bounds<<<1, 128, 0, stream>>>(n2g, bnd, n);

    // layer 0
    k_layer0<<<(n + 3) / 4, 256, 0, stream>>>(rowptr, colsrc, vsrc, norm_dst, norm_src,
                                              W0, b0, hA, n);

    // layers 1,2: gather + MFMA dense (buffers cycle hA <-> aggX)
    int ggather = (n + 3) / 4;
    int ggemm = ((n + 15) / 16 + 3) / 4;
    k_gather<<<ggather, 256, 0, stream>>>(rowptr, colsrc, hA, norm_dst, aggX, n);
    k_gemm<0><<<ggemm, 256, 0, stream>>>(aggX, W1, b1, norm_src, nullptr, hA, nullptr, n);
    k_gather<<<ggather, 256, 0, stream>>>(rowptr, colsrc, hA, norm_dst, aggX, n);
    k_gemm<1><<<ggemm, 256, 0, stream>>>(aggX, W2, b2, nullptr, Wr, nullptr, rbuf, n);

    // readout
    k_mean<<<NGRAPHS, 256, 0, stream>>>(rbuf, bnd, br, out);
}

// Round 12
// 229.492 us; speedup vs baseline: 1.3446x; 1.0042x over previous
//
#include <hip/hip_runtime.h>
#include <hip/hip_bf16.h>

#define NGRAPHS 64
#define RANGE 8192
#define RSHIFT 13
#define CHUNKS 32

typedef unsigned short u16;
typedef unsigned int u32;
typedef unsigned short bf16_t;
using s8v = __attribute__((ext_vector_type(8))) short;   // 8 bf16 (4 VGPRs)
using f4v = __attribute__((ext_vector_type(4))) float;   // MFMA accumulator

__device__ inline float bf2f(bf16_t u) { return __uint_as_float(((unsigned)u) << 16); }
__device__ inline bf16_t f2bf(float f) {
    unsigned x = __float_as_uint(f);
    return (bf16_t)((x + 0x7fffu + ((x >> 16) & 1u)) >> 16);  // RNE
}

// ============ CSR build: bucket partition, per-edge atomics are LDS-only ============

__global__ void k_p0(const int* __restrict__ src, const int* __restrict__ dst,
                     int* __restrict__ dsz, int* __restrict__ ssz, int nr, int E) {
    __shared__ int ld[16], ls[16];
    int tid = threadIdx.x;
    if (tid < 16) { ld[tid] = 0; ls[tid] = 0; }
    __syncthreads();
    int e4 = (blockIdx.x * 256 + tid) * 4;
    if (e4 + 4 <= E) {
        int4 d = *(const int4*)&dst[e4];
        int4 s = *(const int4*)&src[e4];
        atomicAdd(&ld[d.x >> RSHIFT], 1); atomicAdd(&ld[d.y >> RSHIFT], 1);
        atomicAdd(&ld[d.z >> RSHIFT], 1); atomicAdd(&ld[d.w >> RSHIFT], 1);
        atomicAdd(&ls[s.x >> RSHIFT], 1); atomicAdd(&ls[s.y >> RSHIFT], 1);
        atomicAdd(&ls[s.z >> RSHIFT], 1); atomicAdd(&ls[s.w >> RSHIFT], 1);
    } else {
        for (int e = e4; e < E; ++e) {
            atomicAdd(&ld[dst[e] >> RSHIFT], 1);
            atomicAdd(&ls[src[e] >> RSHIFT], 1);
        }
    }
    __syncthreads();
    if (tid < nr) {
        if (ld[tid]) atomicAdd(&dsz[tid], ld[tid]);
        if (ls[tid]) atomicAdd(&ssz[tid], ls[tid]);
    }
}

__global__ void k_pscan(const int* __restrict__ dsz, const int* __restrict__ ssz,
                        int* __restrict__ dbase, int* __restrict__ sbase,
                        int* __restrict__ dcur, int* __restrict__ scur, int nr) {
    if (threadIdx.x == 0) {
        int a = 0;
        for (int r = 0; r < nr; ++r) { dbase[r] = a; dcur[r] = a; a += dsz[r]; }
        dbase[nr] = a;
        a = 0;
        for (int r = 0; r < nr; ++r) { sbase[r] = a; scur[r] = a; a += ssz[r]; }
        sbase[nr] = a;
    }
}

__global__ void k_p1(const int* __restrict__ src, const int* __restrict__ dst,
                     int* __restrict__ dcur, int* __restrict__ scur,
                     u32* __restrict__ ebuf, u16* __restrict__ sbuf, int nr, int E) {
    __shared__ int ldc[16], lsc[16], gdb[16], gsb[16];
    int tid = threadIdx.x;
    if (tid < 16) { ldc[tid] = 0; lsc[tid] = 0; }
    __syncthreads();
    int e4 = (blockIdx.x * 256 + tid) * 4;
    int s[4], d[4], pd[4], ps[4];
    int cnt = 0;
    if (e4 + 4 <= E) {
        int4 dv = *(const int4*)&dst[e4];
        int4 sv = *(const int4*)&src[e4];
        s[0] = sv.x; s[1] = sv.y; s[2] = sv.z; s[3] = sv.w;
        d[0] = dv.x; d[1] = dv.y; d[2] = dv.z; d[3] = dv.w;
        cnt = 4;
    } else {
        for (int e = e4; e < E; ++e) { s[cnt] = src[e]; d[cnt] = dst[e]; ++cnt; }
    }
    for (int i = 0; i < cnt; ++i) {
        pd[i] = atomicAdd(&ldc[d[i] >> RSHIFT], 1);
        ps[i] = atomicAdd(&lsc[s[i] >> RSHIFT], 1);
    }
    __syncthreads();
    if (tid < nr) {
        gdb[tid] = atomicAdd(&dcur[tid], ldc[tid]);
        gsb[tid] = atomicAdd(&scur[tid], lsc[tid]);
    }
    __syncthreads();
    for (int i = 0; i < cnt; ++i) {
        int db = d[i] >> RSHIFT, sb = s[i] >> RSHIFT;
        ebuf[gdb[db] + pd[i]] = ((u32)s[i] << 16) | (u32)d[i];
        sbuf[gsb[sb] + ps[i]] = (u16)s[i];
    }
}

__global__ void k_hist(const u32* __restrict__ ebuf, const u16* __restrict__ sbuf,
                       const int* __restrict__ dbase, const int* __restrict__ sbase,
                       int* __restrict__ cntC_in, int* __restrict__ cntC_out,
                       int nr, int n) {
    __shared__ int hist[RANGE];
    int tid = threadIdx.x, bid = blockIdx.x;
    int type = bid / (nr * CHUNKS);
    int rem = bid - type * nr * CHUNKS;
    int r = rem / CHUNKS, c = rem - r * CHUNKS;
    for (int i = tid; i < RANGE; i += 256) hist[i] = 0;
    __syncthreads();
    int lo = r * RANGE;
    int seg0 = type ? sbase[r] : dbase[r];
    int seg1 = type ? sbase[r + 1] : dbase[r + 1];
    int sz = seg1 - seg0;
    int ce0 = seg0 + (int)((long long)sz * c / CHUNKS);
    int ce1 = seg0 + (int)((long long)sz * (c + 1) / CHUNKS);
    int e = ce0 + tid;
    if (type == 0) {
        for (; e + 768 < ce1; e += 1024) {
            int k0 = ebuf[e] & 0xFFFF, k1 = ebuf[e + 256] & 0xFFFF;
            int k2 = ebuf[e + 512] & 0xFFFF, k3 = ebuf[e + 768] & 0xFFFF;
            atomicAdd(&hist[k0 - lo], 1); atomicAdd(&hist[k1 - lo], 1);
            atomicAdd(&hist[k2 - lo], 1); atomicAdd(&hist[k3 - lo], 1);
        }
        for (; e < ce1; e += 256) atomicAdd(&hist[(ebuf[e] & 0xFFFF) - lo], 1);
    } else {
        for (; e + 768 < ce1; e += 1024) {
            int k0 = sbuf[e], k1 = sbuf[e + 256], k2 = sbuf[e + 512], k3 = sbuf[e + 768];
            atomicAdd(&hist[k0 - lo], 1); atomicAdd(&hist[k1 - lo], 1);
            atomicAdd(&hist[k2 - lo], 1); atomicAdd(&hist[k3 - lo], 1);
        }
        for (; e < ce1; e += 256) atomicAdd(&hist[(int)sbuf[e] - lo], 1);
    }
    __syncthreads();
    int hi = min(n - lo, RANGE);
    int* __restrict__ outb = (type ? cntC_out : cntC_in) + (size_t)c * n + lo;
    for (int i = tid; i < hi; i += 256) outb[i] = hist[i];
}

__device__ inline int block_excl_scan(int v, int tid, int* wavesums, int* block_total) {
    int lane = tid & 63, wave = tid >> 6;
    int incl = v;
    #pragma unroll
    for (int off = 1; off < 64; off <<= 1) {
        int t = __shfl_up(incl, off);
        if (lane >= off) incl += t;
    }
    if (lane == 63) wavesums[wave] = incl;
    __syncthreads();
    int woff = 0;
    #pragma unroll
    for (int w = 0; w < 4; ++w) if (w < wave) woff += wavesums[w];
    *block_total = wavesums[0] + wavesums[1] + wavesums[2] + wavesums[3];
    return incl + woff - v;
}

__global__ void k_scan1(const int* __restrict__ cntC_in, int* __restrict__ cnt_tot_in,
                        int* __restrict__ rowptr, int* __restrict__ blocksums, int n) {
    __shared__ int wavesums[4];
    int tid = threadIdx.x;
    int idx = blockIdx.x * 256 + tid;
    int v = 0;
    if (idx < n) {
        #pragma unroll
        for (int k = 0; k < CHUNKS; ++k) v += cntC_in[(size_t)k * n + idx];
        cnt_tot_in[idx] = v;
    }
    int total;
    int excl = block_excl_scan(v, tid, wavesums, &total);
    if (idx < n) rowptr[idx] = excl;
    if (tid == 0) blocksums[blockIdx.x] = total;
}

__global__ void k_scan2(int* __restrict__ blocksums, int nb) {
    __shared__ int wavesums[4];
    int tid = threadIdx.x;
    int v = (tid < nb) ? blocksums[tid] : 0;
    int total;
    int excl = block_excl_scan(v, tid, wavesums, &total);
    if (tid < nb) blocksums[tid] = excl;
}

__global__ void k_scan3(int* __restrict__ rowptr, const int* __restrict__ blocksums,
                        const int* __restrict__ cntC_in, const int* __restrict__ cntC_out,
                        const int* __restrict__ cnt_tot_in,
                        int* __restrict__ cursorC,
                        float* __restrict__ norm_src, float* __restrict__ norm_dst,
                        float* __restrict__ vsrc, int n, int E) {
    int idx = blockIdx.x * 256 + threadIdx.x;
    if (idx < n) {
        int base = rowptr[idx] + blocksums[blockIdx.x];
        rowptr[idx] = base;
        int dout = 0;
        #pragma unroll
        for (int k = 0; k < CHUNKS; ++k) {
            cursorC[(size_t)k * n + idx] = base;
            base += cntC_in[(size_t)k * n + idx];
            dout += cntC_out[(size_t)k * n + idx];
        }
        float di = (float)cnt_tot_in[idx];
        float ns = rsqrtf(fmaxf((float)dout, 1.0f));
        norm_src[idx] = ns;
        norm_dst[idx] = rsqrtf(fmaxf(di, 1.0f));
        vsrc[idx] = di * ns;
    }
    if (idx == 0) rowptr[n] = E;
}

__global__ void k_fillv2(const u32* __restrict__ ebuf, const int* __restrict__ dbase,
                         const int* __restrict__ cursorC, u16* __restrict__ colsrc,
                         int nr, int n) {
    __shared__ int cur[RANGE];
    int tid = threadIdx.x, bid = blockIdx.x;
    int r = bid / CHUNKS, c = bid - r * CHUNKS;
    int lo = r * RANGE, hi = min(n - lo, RANGE);
    for (int i = tid; i < hi; i += 256) cur[i] = cursorC[(size_t)c * n + lo + i];
    __syncthreads();
    int seg0 = dbase[r], seg1 = dbase[r + 1];
    int sz = seg1 - seg0;
    int ce0 = seg0 + (int)((long long)sz * c / CHUNKS);
    int ce1 = seg0 + (int)((long long)sz * (c + 1) / CHUNKS);
    int e = ce0 + tid;
    for (; e + 768 < ce1; e += 1024) {
        u32 v0 = ebuf[e], v1 = ebuf[e + 256], v2 = ebuf[e + 512], v3 = ebuf[e + 768];
        colsrc[atomicAdd(&cur[(v0 & 0xFFFF) - lo], 1)] = (u16)(v0 >> 16);
        colsrc[atomicAdd(&cur[(v1 & 0xFFFF) - lo], 1)] = (u16)(v1 >> 16);
        colsrc[atomicAdd(&cur[(v2 & 0xFFFF) - lo], 1)] = (u16)(v2 >> 16);
        colsrc[atomicAdd(&cur[(v3 & 0xFFFF) - lo], 1)] = (u16)(v3 >> 16);
    }
    for (; e < ce1; e += 256) {
        u32 v = ebuf[e];
        colsrc[atomicAdd(&cur[(v & 0xFFFF) - lo], 1)] = (u16)(v >> 16);
    }
}

// ============ layer 0: wave-per-node gather + rank-1 dense ============
__global__ void k_layer0(const int* __restrict__ rowptr, const u16* __restrict__ colsrc,
                         const float* __restrict__ vsrc, const float* __restrict__ norm_dst,
                         const float* __restrict__ norm_src,
                         const float* __restrict__ W0, const float* __restrict__ b0,
                         bf16_t* __restrict__ out, int n) {
    int wave = threadIdx.x >> 6, lane = threadIdx.x & 63;
    int i = blockIdx.x * 4 + wave;
    if (i >= n) return;
    int p0 = rowptr[i], pe = rowptr[i + 1];
    float s = 0.0f;
    for (int p = p0 + lane; p < pe; p += 64) s += vsrc[colsrc[p]];
    #pragma unroll
    for (int off = 32; off > 0; off >>= 1) s += __shfl_xor(s, off);
    float v = fmaxf(s * norm_dst[i] * W0[lane] + b0[lane], 0.0f) * norm_src[i];
    out[(size_t)i * 64 + lane] = f2bf(v);
}

// ============ FUSED gather -> LDS A-strip -> MFMA dense ============
// Block: 256 thr / 4 waves; wave owns a 16-node strip (64 nodes/block).
// Gather: half-waves process 2 nodes concurrently, u32 loads (2 bf16 feats/lane).
// LDS A-strip stride 144 B (36 u32) -> max 2-way bank aliasing.
// __launch_bounds__(256,4): 128-VGPR budget (default 1024-thr assumption caps at 64!).
template <int FUSE_DOT>
__global__ __launch_bounds__(256, 4)
void k_fgd(const int* __restrict__ rowptr, const u16* __restrict__ colsrc,
           const bf16_t* __restrict__ hin, const float* __restrict__ norm_dst,
           const float* __restrict__ norm_src,
           const float* __restrict__ W, const float* __restrict__ b,
           const float* __restrict__ Wr,
           bf16_t* __restrict__ hout, float* __restrict__ rout, int n) {
    __shared__ bf16_t Wbf[64 * 64];
    __shared__ float bs[64];
    __shared__ u32 astrip[64 * 36];   // 64 rows, stride 36 u32 = 144 B
    int tid = threadIdx.x;
    #pragma unroll
    for (int it = 0; it < 16; ++it) {
        int idx = tid + it * 256;
        Wbf[idx] = f2bf(W[idx]);
    }
    if (tid < 64) bs[tid] = b[tid];
    __syncthreads();  // only block-wide sync; all later LDS use is wave-local

    int wave = tid >> 6, lane = tid & 63;
    int quad = lane >> 4, l16 = lane & 15;
    int half = lane >> 5, f = lane & 31, hb = half * 32;

    // B fragments from LDS (one-time)
    s8v bfrag[4][2];
    #pragma unroll
    for (int t = 0; t < 4; ++t)
        #pragma unroll
        for (int c = 0; c < 2; ++c)
            #pragma unroll
            for (int jj = 0; jj < 8; ++jj)
                bfrag[t][c][jj] = (short)Wbf[(c * 32 + quad * 8 + jj) * 64 + t * 16 + l16];

    int m0 = (blockIdx.x * 4 + wave) * 16;
    if (m0 >= n) return;

    const u32* __restrict__ hp = (const u32*)hin;  // row c -> c*32 + f

    // gather 16 rows, 2 at a time (half-waves independent; divergence = max iters)
    for (int t = 0; t < 16; t += 2) {
        int i = m0 + t + half;
        int p0 = 0, deg = 0;
        if (i < n) { p0 = rowptr[i]; deg = rowptr[i + 1] - p0; }
        float s0 = 0.f, s1 = 0.f, s2 = 0.f, s3 = 0.f;
        float s4 = 0.f, s5 = 0.f, s6 = 0.f, s7 = 0.f;
        for (int cb = 0; cb < deg; cb += 32) {
            int m = min(32, deg - cb);
            int col = (f < m) ? (int)colsrc[p0 + cb + f] : 0;
            int e = 0;
            for (; e + 4 <= m; e += 4) {
                int c0 = __shfl(col, hb + e),     c1 = __shfl(col, hb + e + 1);
                int c2 = __shfl(col, hb + e + 2), c3 = __shfl(col, hb + e + 3);
                u32 v0 = hp[c0 * 32 + f], v1 = hp[c1 * 32 + f];
                u32 v2 = hp[c2 * 32 + f], v3 = hp[c3 * 32 + f];
                s0 += __uint_as_float(v0 << 16); s1 += __uint_as_float(v0 & 0xFFFF0000u);
                s2 += __uint_as_float(v1 << 16); s3 += __uint_as_float(v1 & 0xFFFF0000u);
                s4 += __uint_as_float(v2 << 16); s5 += __uint_as_float(v2 & 0xFFFF0000u);
                s6 += __uint_as_float(v3 << 16); s7 += __uint_as_float(v3 & 0xFFFF0000u);
            }
            for (; e < m; ++e) {
                int c = __shfl(col, hb + e);
                u32 v = hp[c * 32 + f];
                s0 += __uint_as_float(v << 16); s1 += __uint_as_float(v & 0xFFFF0000u);
            }
        }
        u32 packed = 0;
        if (i < n) {
            float nd = norm_dst[i];
            float flo = ((s0 + s2) + (s4 + s6)) * nd;
            float fhi = ((s1 + s3) + (s5 + s7)) * nd;
            packed = ((u32)f2bf(fhi) << 16) | (u32)f2bf(flo);
        }
        astrip[(wave * 16 + t + half) * 36 + f] = packed;  // conflict-free ds_write_b32
    }
    asm volatile("s_waitcnt lgkmcnt(0)" ::: "memory");  // wave-local LDS RAW fence

    // A fragments from LDS strip
    const char* ap = (const char*)astrip + (wave * 16 + l16) * 144 + quad * 16;
    s8v a0 = *(const s8v*)ap;          // k in [0,32)
    s8v a1 = *(const s8v*)(ap + 64);   // k in [32,64)

    f4v acc[4];
    #pragma unroll
    for (int t = 0; t < 4; ++t) { acc[t][0] = 0.f; acc[t][1] = 0.f; acc[t][2] = 0.f; acc[t][3] = 0.f; }
    #pragma unroll
    for (int t = 0; t < 4; ++t) {
        acc[t] = __builtin_amdgcn_mfma_f32_16x16x32_bf16(a0, bfrag[t][0], acc[t], 0, 0, 0);
        acc[t] = __builtin_amdgcn_mfma_f32_16x16x32_bf16(a1, bfrag[t][1], acc[t], 0, 0, 0);
    }

    if (FUSE_DOT) {
        float p0 = 0.f, p1 = 0.f, p2 = 0.f, p3 = 0.f;
        #pragma unroll
        for (int t = 0; t < 4; ++t) {
            float wr = Wr[t * 16 + l16];
            float bias = bs[t * 16 + l16];
            p0 = fmaf(fmaxf(acc[t][0] + bias, 0.f), wr, p0);
            p1 = fmaf(fmaxf(acc[t][1] + bias, 0.f), wr, p1);
            p2 = fmaf(fmaxf(acc[t][2] + bias, 0.f), wr, p2);
            p3 = fmaf(fmaxf(acc[t][3] + bias, 0.f), wr, p3);
        }
        float pr[4] = {p0, p1, p2, p3};
        #pragma unroll
        for (int r = 0; r < 4; ++r) {
            float v = pr[r];
            v += __shfl_xor(v, 1); v += __shfl_xor(v, 2);
            v += __shfl_xor(v, 4); v += __shfl_xor(v, 8);
            int i = m0 + quad * 4 + r;
            if (l16 == 0 && i < n) rout[i] = v;
        }
    } else {
        float ns[4];
        #pragma unroll
        for (int r = 0; r < 4; ++r) {
            int i = m0 + quad * 4 + r;
            ns[r] = norm_src[i < n ? i : n - 1];
        }
        #pragma unroll
        for (int t = 0; t < 4; ++t) {
            float bias = bs[t * 16 + l16];
            #pragma unroll
            for (int r = 0; r < 4; ++r) {
                int i = m0 + quad * 4 + r;
                if (i < n) {
                    float v = fmaxf(acc[t][r] + bias, 0.f) * ns[r];
                    hout[(size_t)i * 64 + t * 16 + l16] = f2bf(v);
                }
            }
        }
    }
}

// ============ readout (bounds fused) ============
__global__ void k_mean(const float* __restrict__ r, const int* __restrict__ n2g,
                       const float* __restrict__ br, float* __restrict__ out, int n) {
    __shared__ float ssum[4];
    __shared__ int sb[2];
    int g = blockIdx.x, tid = threadIdx.x;
    if (tid < 2) {
        int target = g + tid;
        int lo = 0, hi = n;
        while (lo < hi) { int mid = (lo + hi) >> 1; if (n2g[mid] < target) lo = mid + 1; else hi = mid; }
        sb[tid] = lo;
    }
    __syncthreads();
    int lo = sb[0], hi = sb[1];
    float s = 0.0f;
    for (int i = lo + tid; i < hi; i += 256) s += r[i];
    #pragma unroll
    for (int off = 32; off > 0; off >>= 1) s += __shfl_down(s, off);
    int wave = tid >> 6;
    if ((tid & 63) == 0) ssum[wave] = s;
    __syncthreads();
    if (tid == 0) {
        float S = ssum[0] + ssum[1] + ssum[2] + ssum[3];
        out[g] = S / fmaxf((float)(hi - lo), 1.0f) + br[0];
    }
}

extern "C" void kernel_launch(void* const* d_in, const int* in_sizes, int n_in,
                              void* d_out, int out_size, void* d_ws, size_t ws_size,
                              hipStream_t stream) {
    const int* src = (const int*)d_in[0];
    const int* dst = (const int*)d_in[1];
    const int* n2g = (const int*)d_in[2];
    const float* W0 = (const float*)d_in[3];
    const float* b0 = (const float*)d_in[4];
    const float* W1 = (const float*)d_in[5];
    const float* b1 = (const float*)d_in[6];
    const float* W2 = (const float*)d_in[7];
    const float* b2 = (const float*)d_in[8];
    const float* Wr = (const float*)d_in[9];
    const float* br = (const float*)d_in[10];
    float* out = (float*)d_out;

    int E = in_sizes[0];
    int n = in_sizes[2];               // 50000 (< 65536: u16 packing valid)
    int nb = (n + 255) / 256;          // 196
    int nr = (n + RANGE - 1) / RANGE;  // 7

    char* base = (char*)d_ws;
    size_t off = 0;
    auto alloc = [&](size_t bytes) -> void* {
        off = (off + 255) & ~(size_t)255;
        void* p = base + off;
        off += bytes;
        return p;
    };
    int* meta = (int*)alloc(96 * sizeof(int));
    int* dsz = meta;
    int* ssz = meta + 16;
    int* dbase = meta + 32;
    int* sbase = meta + 48;
    int* dcur = meta + 64;
    int* scur = meta + 80;
    u32* ebuf = (u32*)alloc((size_t)E * sizeof(u32));
    u16* sbuf = (u16*)alloc((size_t)E * sizeof(u16));
    int* cntC_in = (int*)alloc((size_t)CHUNKS * n * sizeof(int));
    int* cntC_out = (int*)alloc((size_t)CHUNKS * n * sizeof(int));
    int* cursorC = (int*)alloc((size_t)CHUNKS * n * sizeof(int));
    int* cnt_tot_in = (int*)alloc((size_t)n * sizeof(int));
    int* rowptr = (int*)alloc((size_t)(n + 1) * sizeof(int));
    int* blocksums = (int*)alloc(256 * sizeof(int));
    u16* colsrc = (u16*)alloc((size_t)E * sizeof(u16));
    float* norm_src = (float*)alloc((size_t)n * sizeof(float));
    float* norm_dst = (float*)alloc((size_t)n * sizeof(float));
    float* vsrc = (float*)alloc((size_t)n * sizeof(float));
    float* rbuf = (float*)alloc((size_t)n * sizeof(float));
    bf16_t* hA = (bf16_t*)alloc((size_t)n * 64 * sizeof(bf16_t));
    bf16_t* hX = (bf16_t*)alloc((size_t)n * 64 * sizeof(bf16_t));

    hipMemsetAsync(meta, 0, 32 * sizeof(int), stream);  // dsz + ssz only

    int gP = (E + 1023) / 1024;
    k_p0<<<gP, 256, 0, stream>>>(src, dst, dsz, ssz, nr, E);
    k_pscan<<<1, 64, 0, stream>>>(dsz, ssz, dbase, sbase, dcur, scur, nr);
    k_p1<<<gP, 256, 0, stream>>>(src, dst, dcur, scur, ebuf, sbuf, nr, E);
    k_hist<<<2 * nr * CHUNKS, 256, 0, stream>>>(ebuf, sbuf, dbase, sbase,
                                                cntC_in, cntC_out, nr, n);
    k_scan1<<<nb, 256, 0, stream>>>(cntC_in, cnt_tot_in, rowptr, blocksums, n);
    k_scan2<<<1, 256, 0, stream>>>(blocksums, nb);
    k_scan3<<<nb, 256, 0, stream>>>(rowptr, blocksums, cntC_in, cntC_out, cnt_tot_in,
                                    cursorC, norm_src, norm_dst, vsrc, n, E);
    k_fillv2<<<nr * CHUNKS, 256, 0, stream>>>(ebuf, dbase, cursorC, colsrc, nr, n);

    // layer 0
    k_layer0<<<(n + 3) / 4, 256, 0, stream>>>(rowptr, colsrc, vsrc, norm_dst, norm_src,
                                              W0, b0, hA, n);

    // layers 1,2: fused gather + MFMA dense
    int gfgd = (n + 63) / 64;
    k_fgd<0><<<gfgd, 256, 0, stream>>>(rowptr, colsrc, hA, norm_dst, norm_src,
                                       W1, b1, nullptr, hX, nullptr, n);
    k_fgd<1><<<gfgd, 256, 0, stream>>>(rowptr, colsrc, hX, norm_dst, nullptr,
                                       W2, b2, Wr, nullptr, rbuf, n);

    // readout
    k_mean<<<NGRAPHS, 256, 0, stream>>>(rbuf, n2g, br, out, n);
}

// Round 13
// 213.752 us; speedup vs baseline: 1.4436x; 1.0736x over previous
//
#include <hip/hip_runtime.h>
#include <hip/hip_bf16.h>

#define NGRAPHS 64
#define RANGE 8192
#define RSHIFT 13
#define CHUNKS 32

typedef unsigned short u16;
typedef unsigned int u32;
typedef unsigned long long u64;
typedef unsigned short bf16_t;
using s8v = __attribute__((ext_vector_type(8))) short;   // 8 bf16 (4 VGPRs)
using f4v = __attribute__((ext_vector_type(4))) float;   // MFMA accumulator

__device__ inline float bf2f(bf16_t u) { return __uint_as_float(((unsigned)u) << 16); }
__device__ inline bf16_t f2bf(float f) {
    unsigned x = __float_as_uint(f);
    return (bf16_t)((x + 0x7fffu + ((x >> 16) & 1u)) >> 16);  // RNE
}
__device__ inline void acc4(u64 v, float& a, float& b, float& c, float& d) {
    u32 lo = (u32)v, hi = (u32)(v >> 32);
    a += __uint_as_float(lo << 16);
    b += __uint_as_float(lo & 0xFFFF0000u);
    c += __uint_as_float(hi << 16);
    d += __uint_as_float(hi & 0xFFFF0000u);
}

// ============ CSR build: bucket partition, per-edge atomics are LDS-only ============

__global__ void k_p0(const int* __restrict__ src, const int* __restrict__ dst,
                     int* __restrict__ dsz, int* __restrict__ ssz, int nr, int E) {
    __shared__ int ld[16], ls[16];
    int tid = threadIdx.x;
    if (tid < 16) { ld[tid] = 0; ls[tid] = 0; }
    __syncthreads();
    int e4 = (blockIdx.x * 256 + tid) * 4;
    if (e4 + 4 <= E) {
        int4 d = *(const int4*)&dst[e4];
        int4 s = *(const int4*)&src[e4];
        atomicAdd(&ld[d.x >> RSHIFT], 1); atomicAdd(&ld[d.y >> RSHIFT], 1);
        atomicAdd(&ld[d.z >> RSHIFT], 1); atomicAdd(&ld[d.w >> RSHIFT], 1);
        atomicAdd(&ls[s.x >> RSHIFT], 1); atomicAdd(&ls[s.y >> RSHIFT], 1);
        atomicAdd(&ls[s.z >> RSHIFT], 1); atomicAdd(&ls[s.w >> RSHIFT], 1);
    } else {
        for (int e = e4; e < E; ++e) {
            atomicAdd(&ld[dst[e] >> RSHIFT], 1);
            atomicAdd(&ls[src[e] >> RSHIFT], 1);
        }
    }
    __syncthreads();
    if (tid < nr) {
        if (ld[tid]) atomicAdd(&dsz[tid], ld[tid]);
        if (ls[tid]) atomicAdd(&ssz[tid], ls[tid]);
    }
}

__global__ void k_pscan(const int* __restrict__ dsz, const int* __restrict__ ssz,
                        int* __restrict__ dbase, int* __restrict__ sbase,
                        int* __restrict__ dcur, int* __restrict__ scur, int nr) {
    if (threadIdx.x == 0) {
        int a = 0;
        for (int r = 0; r < nr; ++r) { dbase[r] = a; dcur[r] = a; a += dsz[r]; }
        dbase[nr] = a;
        a = 0;
        for (int r = 0; r < nr; ++r) { sbase[r] = a; scur[r] = a; a += ssz[r]; }
        sbase[nr] = a;
    }
}

__global__ void k_p1(const int* __restrict__ src, const int* __restrict__ dst,
                     int* __restrict__ dcur, int* __restrict__ scur,
                     u32* __restrict__ ebuf, u16* __restrict__ sbuf, int nr, int E) {
    __shared__ int ldc[16], lsc[16], gdb[16], gsb[16];
    int tid = threadIdx.x;
    if (tid < 16) { ldc[tid] = 0; lsc[tid] = 0; }
    __syncthreads();
    int e4 = (blockIdx.x * 256 + tid) * 4;
    int s[4], d[4], pd[4], ps[4];
    int cnt = 0;
    if (e4 + 4 <= E) {
        int4 dv = *(const int4*)&dst[e4];
        int4 sv = *(const int4*)&src[e4];
        s[0] = sv.x; s[1] = sv.y; s[2] = sv.z; s[3] = sv.w;
        d[0] = dv.x; d[1] = dv.y; d[2] = dv.z; d[3] = dv.w;
        cnt = 4;
    } else {
        for (int e = e4; e < E; ++e) { s[cnt] = src[e]; d[cnt] = dst[e]; ++cnt; }
    }
    for (int i = 0; i < cnt; ++i) {
        pd[i] = atomicAdd(&ldc[d[i] >> RSHIFT], 1);
        ps[i] = atomicAdd(&lsc[s[i] >> RSHIFT], 1);
    }
    __syncthreads();
    if (tid < nr) {
        gdb[tid] = atomicAdd(&dcur[tid], ldc[tid]);
        gsb[tid] = atomicAdd(&scur[tid], lsc[tid]);
    }
    __syncthreads();
    for (int i = 0; i < cnt; ++i) {
        int db = d[i] >> RSHIFT, sb = s[i] >> RSHIFT;
        ebuf[gdb[db] + pd[i]] = ((u32)s[i] << 16) | (u32)d[i];
        sbuf[gsb[sb] + ps[i]] = (u16)s[i];
    }
}

__global__ void k_hist(const u32* __restrict__ ebuf, const u16* __restrict__ sbuf,
                       const int* __restrict__ dbase, const int* __restrict__ sbase,
                       int* __restrict__ cntC_in, int* __restrict__ cntC_out,
                       int nr, int n) {
    __shared__ int hist[RANGE];
    int tid = threadIdx.x, bid = blockIdx.x;
    int type = bid / (nr * CHUNKS);
    int rem = bid - type * nr * CHUNKS;
    int r = rem / CHUNKS, c = rem - r * CHUNKS;
    for (int i = tid; i < RANGE; i += 256) hist[i] = 0;
    __syncthreads();
    int lo = r * RANGE;
    int seg0 = type ? sbase[r] : dbase[r];
    int seg1 = type ? sbase[r + 1] : dbase[r + 1];
    int sz = seg1 - seg0;
    int ce0 = seg0 + (int)((long long)sz * c / CHUNKS);
    int ce1 = seg0 + (int)((long long)sz * (c + 1) / CHUNKS);
    int e = ce0 + tid;
    if (type == 0) {
        for (; e + 768 < ce1; e += 1024) {
            int k0 = ebuf[e] & 0xFFFF, k1 = ebuf[e + 256] & 0xFFFF;
            int k2 = ebuf[e + 512] & 0xFFFF, k3 = ebuf[e + 768] & 0xFFFF;
            atomicAdd(&hist[k0 - lo], 1); atomicAdd(&hist[k1 - lo], 1);
            atomicAdd(&hist[k2 - lo], 1); atomicAdd(&hist[k3 - lo], 1);
        }
        for (; e < ce1; e += 256) atomicAdd(&hist[(ebuf[e] & 0xFFFF) - lo], 1);
    } else {
        for (; e + 768 < ce1; e += 1024) {
            int k0 = sbuf[e], k1 = sbuf[e + 256], k2 = sbuf[e + 512], k3 = sbuf[e + 768];
            atomicAdd(&hist[k0 - lo], 1); atomicAdd(&hist[k1 - lo], 1);
            atomicAdd(&hist[k2 - lo], 1); atomicAdd(&hist[k3 - lo], 1);
        }
        for (; e < ce1; e += 256) atomicAdd(&hist[(int)sbuf[e] - lo], 1);
    }
    __syncthreads();
    int hi = min(n - lo, RANGE);
    int* __restrict__ outb = (type ? cntC_out : cntC_in) + (size_t)c * n + lo;
    for (int i = tid; i < hi; i += 256) outb[i] = hist[i];
}

__device__ inline int block_excl_scan(int v, int tid, int* wavesums, int* block_total) {
    int lane = tid & 63, wave = tid >> 6;
    int incl = v;
    #pragma unroll
    for (int off = 1; off < 64; off <<= 1) {
        int t = __shfl_up(incl, off);
        if (lane >= off) incl += t;
    }
    if (lane == 63) wavesums[wave] = incl;
    __syncthreads();
    int woff = 0;
    #pragma unroll
    for (int w = 0; w < 4; ++w) if (w < wave) woff += wavesums[w];
    *block_total = wavesums[0] + wavesums[1] + wavesums[2] + wavesums[3];
    return incl + woff - v;
}

__global__ void k_scan1(const int* __restrict__ cntC_in, int* __restrict__ cnt_tot_in,
                        int* __restrict__ rowptr, int* __restrict__ blocksums, int n) {
    __shared__ int wavesums[4];
    int tid = threadIdx.x;
    int idx = blockIdx.x * 256 + tid;
    int v = 0;
    if (idx < n) {
        #pragma unroll
        for (int k = 0; k < CHUNKS; ++k) v += cntC_in[(size_t)k * n + idx];
        cnt_tot_in[idx] = v;
    }
    int total;
    int excl = block_excl_scan(v, tid, wavesums, &total);
    if (idx < n) rowptr[idx] = excl;
    if (tid == 0) blocksums[blockIdx.x] = total;
}

// scan3 with scan2 folded in: every block redundantly excl-scans blocksums (nb<=256)
__global__ void k_scan3(int* __restrict__ rowptr, const int* __restrict__ blocksums,
                        const int* __restrict__ cntC_in, const int* __restrict__ cntC_out,
                        const int* __restrict__ cnt_tot_in,
                        int* __restrict__ cursorC,
                        float* __restrict__ norm_src, float* __restrict__ norm_dst,
                        float* __restrict__ vsrc, int nb, int n, int E) {
    __shared__ int wavesums[4];
    __shared__ int sbs[256];
    int tid = threadIdx.x;
    int bv = (tid < nb) ? blocksums[tid] : 0;
    int total;
    int bexcl = block_excl_scan(bv, tid, wavesums, &total);
    sbs[tid] = bexcl;
    __syncthreads();
    int blockoff = sbs[blockIdx.x];

    int idx = blockIdx.x * 256 + tid;
    if (idx < n) {
        int base = rowptr[idx] + blockoff;
        rowptr[idx] = base;
        int dout = 0;
        #pragma unroll
        for (int k = 0; k < CHUNKS; ++k) {
            cursorC[(size_t)k * n + idx] = base;
            base += cntC_in[(size_t)k * n + idx];
            dout += cntC_out[(size_t)k * n + idx];
        }
        float di = (float)cnt_tot_in[idx];
        float ns = rsqrtf(fmaxf((float)dout, 1.0f));
        norm_src[idx] = ns;
        norm_dst[idx] = rsqrtf(fmaxf(di, 1.0f));
        vsrc[idx] = di * ns;
    }
    if (idx == 0) rowptr[n] = E;
}

__global__ void k_fillv2(const u32* __restrict__ ebuf, const int* __restrict__ dbase,
                         const int* __restrict__ cursorC, u16* __restrict__ colsrc,
                         int nr, int n) {
    __shared__ int cur[RANGE];
    int tid = threadIdx.x, bid = blockIdx.x;
    int r = bid / CHUNKS, c = bid - r * CHUNKS;
    int lo = r * RANGE, hi = min(n - lo, RANGE);
    for (int i = tid; i < hi; i += 256) cur[i] = cursorC[(size_t)c * n + lo + i];
    __syncthreads();
    int seg0 = dbase[r], seg1 = dbase[r + 1];
    int sz = seg1 - seg0;
    int ce0 = seg0 + (int)((long long)sz * c / CHUNKS);
    int ce1 = seg0 + (int)((long long)sz * (c + 1) / CHUNKS);
    int e = ce0 + tid;
    for (; e + 768 < ce1; e += 1024) {
        u32 v0 = ebuf[e], v1 = ebuf[e + 256], v2 = ebuf[e + 512], v3 = ebuf[e + 768];
        colsrc[atomicAdd(&cur[(v0 & 0xFFFF) - lo], 1)] = (u16)(v0 >> 16);
        colsrc[atomicAdd(&cur[(v1 & 0xFFFF) - lo], 1)] = (u16)(v1 >> 16);
        colsrc[atomicAdd(&cur[(v2 & 0xFFFF) - lo], 1)] = (u16)(v2 >> 16);
        colsrc[atomicAdd(&cur[(v3 & 0xFFFF) - lo], 1)] = (u16)(v3 >> 16);
    }
    for (; e < ce1; e += 256) {
        u32 v = ebuf[e];
        colsrc[atomicAdd(&cur[(v & 0xFFFF) - lo], 1)] = (u16)(v >> 16);
    }
}

// ============ layer 0: quarter-wave per node (16 lanes), u64 feat stores ============
__global__ void k_layer0(const int* __restrict__ rowptr, const u16* __restrict__ colsrc,
                         const float* __restrict__ vsrc, const float* __restrict__ norm_dst,
                         const float* __restrict__ norm_src,
                         const float* __restrict__ W0, const float* __restrict__ b0,
                         bf16_t* __restrict__ out, int n) {
    int wave = threadIdx.x >> 6, lane = threadIdx.x & 63;
    int qw = lane >> 4, f = lane & 15;
    int i = blockIdx.x * 16 + wave * 4 + qw;
    if (i >= n) return;
    int p0 = rowptr[i], pe = rowptr[i + 1];
    float s = 0.0f;
    for (int p = p0 + f; p < pe; p += 16) s += vsrc[colsrc[p]];
    #pragma unroll
    for (int off = 1; off < 16; off <<= 1) s += __shfl_xor(s, off);  // 16-lane sum
    float nd = norm_dst[i], ns = norm_src[i];
    float4 w = ((const float4*)W0)[f];
    float4 bb = ((const float4*)b0)[f];
    float a = s * nd;
    float v0 = fmaxf(a * w.x + bb.x, 0.0f) * ns;
    float v1 = fmaxf(a * w.y + bb.y, 0.0f) * ns;
    float v2 = fmaxf(a * w.z + bb.z, 0.0f) * ns;
    float v3 = fmaxf(a * w.w + bb.w, 0.0f) * ns;
    u32 plo = ((u32)f2bf(v1) << 16) | (u32)f2bf(v0);
    u32 phi = ((u32)f2bf(v3) << 16) | (u32)f2bf(v2);
    *(u64*)&out[(size_t)i * 64 + f * 4] = ((u64)phi << 32) | plo;
}

// ============ FUSED gather -> LDS A-strip -> MFMA dense ============
// Quarter-wave gather: 16 lanes x u64 = one 128 B row per quarter -> 4 rows per
// wave VMEM instruction; unroll 8 -> ~32 loads in flight per wave.
template <int FUSE_DOT>
__global__ __launch_bounds__(256, 4)
void k_fgd(const int* __restrict__ rowptr, const u16* __restrict__ colsrc,
           const bf16_t* __restrict__ hin, const float* __restrict__ norm_dst,
           const float* __restrict__ norm_src,
           const float* __restrict__ W, const float* __restrict__ b,
           const float* __restrict__ Wr,
           bf16_t* __restrict__ hout, float* __restrict__ rout, int n) {
    __shared__ bf16_t Wbf[64 * 64];
    __shared__ float bs[64];
    __shared__ u32 astrip[64 * 36];   // 64 rows, stride 36 u32 = 144 B
    int tid = threadIdx.x;
    #pragma unroll
    for (int it = 0; it < 16; ++it) {
        int idx = tid + it * 256;
        Wbf[idx] = f2bf(W[idx]);
    }
    if (tid < 64) bs[tid] = b[tid];
    __syncthreads();  // only block-wide sync; later LDS use is wave-local

    int wave = tid >> 6, lane = tid & 63;
    int quad = lane >> 4, l16 = lane & 15;
    int qw = lane >> 4, f = lane & 15, qb = qw << 4;

    // B fragments from LDS (one-time)
    s8v bfrag[4][2];
    #pragma unroll
    for (int t = 0; t < 4; ++t)
        #pragma unroll
        for (int c = 0; c < 2; ++c)
            #pragma unroll
            for (int jj = 0; jj < 8; ++jj)
                bfrag[t][c][jj] = (short)Wbf[(c * 32 + qw * 8 + jj) * 64 + t * 16 + l16];

    int m0 = (blockIdx.x * 4 + wave) * 16;
    if (m0 >= n) return;

    const u64* __restrict__ hp = (const u64*)hin;  // row c -> c*16 + f (u64 units)

    // gather 16 rows, 4 at a time (quarter-waves independent)
    for (int t = 0; t < 16; t += 4) {
        int i = m0 + t + qw;
        int p0 = 0, deg = 0;
        if (i < n) { p0 = rowptr[i]; deg = rowptr[i + 1] - p0; }
        float s0 = 0.f, s1 = 0.f, s2 = 0.f, s3 = 0.f;
        float t0 = 0.f, t1 = 0.f, t2 = 0.f, t3 = 0.f;
        for (int cb = 0; cb < deg; cb += 16) {
            int m = min(16, deg - cb);
            int col = (f < m) ? (int)colsrc[p0 + cb + f] : 0;
            int e = 0;
            for (; e + 8 <= m; e += 8) {
                int c0 = __shfl(col, qb + e),     c1 = __shfl(col, qb + e + 1);
                int c2 = __shfl(col, qb + e + 2), c3 = __shfl(col, qb + e + 3);
                int c4 = __shfl(col, qb + e + 4), c5 = __shfl(col, qb + e + 5);
                int c6 = __shfl(col, qb + e + 6), c7 = __shfl(col, qb + e + 7);
                u64 v0 = hp[c0 * 16 + f], v1 = hp[c1 * 16 + f];
                u64 v2 = hp[c2 * 16 + f], v3 = hp[c3 * 16 + f];
                u64 v4 = hp[c4 * 16 + f], v5 = hp[c5 * 16 + f];
                u64 v6 = hp[c6 * 16 + f], v7 = hp[c7 * 16 + f];
                acc4(v0, s0, s1, s2, s3); acc4(v1, t0, t1, t2, t3);
                acc4(v2, s0, s1, s2, s3); acc4(v3, t0, t1, t2, t3);
                acc4(v4, s0, s1, s2, s3); acc4(v5, t0, t1, t2, t3);
                acc4(v6, s0, s1, s2, s3); acc4(v7, t0, t1, t2, t3);
            }
            for (; e < m; ++e) {
                int c = __shfl(col, qb + e);
                acc4(hp[c * 16 + f], s0, s1, s2, s3);
            }
        }
        u64 packed = 0;
        if (i < n) {
            float nd = norm_dst[i];
            float f0 = (s0 + t0) * nd, f1 = (s1 + t1) * nd;
            float f2 = (s2 + t2) * nd, f3 = (s3 + t3) * nd;
            u32 plo = ((u32)f2bf(f1) << 16) | (u32)f2bf(f0);
            u32 phi = ((u32)f2bf(f3) << 16) | (u32)f2bf(f2);
            packed = ((u64)phi << 32) | plo;
        }
        *(u64*)&astrip[(wave * 16 + t + qw) * 36 + f * 2] = packed;
    }
    asm volatile("s_waitcnt lgkmcnt(0)" ::: "memory");  // wave-local LDS RAW fence

    // A fragments from LDS strip (row stride 144 B, linear feat order)
    const char* ap = (const char*)astrip + (wave * 16 + l16) * 144 + quad * 16;
    s8v a0 = *(const s8v*)ap;          // k in [0,32)
    s8v a1 = *(const s8v*)(ap + 64);   // k in [32,64)

    f4v acc[4];
    #pragma unroll
    for (int t = 0; t < 4; ++t) { acc[t][0] = 0.f; acc[t][1] = 0.f; acc[t][2] = 0.f; acc[t][3] = 0.f; }
    #pragma unroll
    for (int t = 0; t < 4; ++t) {
        acc[t] = __builtin_amdgcn_mfma_f32_16x16x32_bf16(a0, bfrag[t][0], acc[t], 0, 0, 0);
        acc[t] = __builtin_amdgcn_mfma_f32_16x16x32_bf16(a1, bfrag[t][1], acc[t], 0, 0, 0);
    }

    if (FUSE_DOT) {
        float p0 = 0.f, p1 = 0.f, p2 = 0.f, p3 = 0.f;
        #pragma unroll
        for (int t = 0; t < 4; ++t) {
            float wr = Wr[t * 16 + l16];
            float bias = bs[t * 16 + l16];
            p0 = fmaf(fmaxf(acc[t][0] + bias, 0.f), wr, p0);
            p1 = fmaf(fmaxf(acc[t][1] + bias, 0.f), wr, p1);
            p2 = fmaf(fmaxf(acc[t][2] + bias, 0.f), wr, p2);
            p3 = fmaf(fmaxf(acc[t][3] + bias, 0.f), wr, p3);
        }
        float pr[4] = {p0, p1, p2, p3};
        #pragma unroll
        for (int r = 0; r < 4; ++r) {
            float v = pr[r];
            v += __shfl_xor(v, 1); v += __shfl_xor(v, 2);
            v += __shfl_xor(v, 4); v += __shfl_xor(v, 8);
            int i = m0 + quad * 4 + r;
            if (l16 == 0 && i < n) rout[i] = v;
        }
    } else {
        float ns[4];
        #pragma unroll
        for (int r = 0; r < 4; ++r) {
            int i = m0 + quad * 4 + r;
            ns[r] = norm_src[i < n ? i : n - 1];
        }
        #pragma unroll
        for (int t = 0; t < 4; ++t) {
            float bias = bs[t * 16 + l16];
            #pragma unroll
            for (int r = 0; r < 4; ++r) {
                int i = m0 + quad * 4 + r;
                if (i < n) {
                    float v = fmaxf(acc[t][r] + bias, 0.f) * ns[r];
                    hout[(size_t)i * 64 + t * 16 + l16] = f2bf(v);
                }
            }
        }
    }
}

// ============ readout (bounds fused) ============
__global__ void k_mean(const float* __restrict__ r, const int* __restrict__ n2g,
                       const float* __restrict__ br, float* __restrict__ out, int n) {
    __shared__ float ssum[4];
    __shared__ int sb[2];
    int g = blockIdx.x, tid = threadIdx.x;
    if (tid < 2) {
        int target = g + tid;
        int lo = 0, hi = n;
        while (lo < hi) { int mid = (lo + hi) >> 1; if (n2g[mid] < target) lo = mid + 1; else hi = mid; }
        sb[tid] = lo;
    }
    __syncthreads();
    int lo = sb[0], hi = sb[1];
    float s = 0.0f;
    for (int i = lo + tid; i < hi; i += 256) s += r[i];
    #pragma unroll
    for (int off = 32; off > 0; off >>= 1) s += __shfl_down(s, off);
    int wave = tid >> 6;
    if ((tid & 63) == 0) ssum[wave] = s;
    __syncthreads();
    if (tid == 0) {
        float S = ssum[0] + ssum[1] + ssum[2] + ssum[3];
        out[g] = S / fmaxf((float)(hi - lo), 1.0f) + br[0];
    }
}

extern "C" void kernel_launch(void* const* d_in, const int* in_sizes, int n_in,
                              void* d_out, int out_size, void* d_ws, size_t ws_size,
                              hipStream_t stream) {
    const int* src = (const int*)d_in[0];
    const int* dst = (const int*)d_in[1];
    const int* n2g = (const int*)d_in[2];
    const float* W0 = (const float*)d_in[3];
    const float* b0 = (const float*)d_in[4];
    const float* W1 = (const float*)d_in[5];
    const float* b1 = (const float*)d_in[6];
    const float* W2 = (const float*)d_in[7];
    const float* b2 = (const float*)d_in[8];
    const float* Wr = (const float*)d_in[9];
    const float* br = (const float*)d_in[10];
    float* out = (float*)d_out;

    int E = in_sizes[0];
    int n = in_sizes[2];               // 50000 (< 65536: u16 packing valid)
    int nb = (n + 255) / 256;          // 196 (<= 256 for merged scan)
    int nr = (n + RANGE - 1) / RANGE;  // 7

    char* base = (char*)d_ws;
    size_t off = 0;
    auto alloc = [&](size_t bytes) -> void* {
        off = (off + 255) & ~(size_t)255;
        void* p = base + off;
        off += bytes;
        return p;
    };
    int* meta = (int*)alloc(96 * sizeof(int));
    int* dsz = meta;
    int* ssz = meta + 16;
    int* dbase = meta + 32;
    int* sbase = meta + 48;
    int* dcur = meta + 64;
    int* scur = meta + 80;
    u32* ebuf = (u32*)alloc((size_t)E * sizeof(u32));
    u16* sbuf = (u16*)alloc((size_t)E * sizeof(u16));
    int* cntC_in = (int*)alloc((size_t)CHUNKS * n * sizeof(int));
    int* cntC_out = (int*)alloc((size_t)CHUNKS * n * sizeof(int));
    int* cursorC = (int*)alloc((size_t)CHUNKS * n * sizeof(int));
    int* cnt_tot_in = (int*)alloc((size_t)n * sizeof(int));
    int* rowptr = (int*)alloc((size_t)(n + 1) * sizeof(int));
    int* blocksums = (int*)alloc(256 * sizeof(int));
    u16* colsrc = (u16*)alloc((size_t)E * sizeof(u16));
    float* norm_src = (float*)alloc((size_t)n * sizeof(float));
    float* norm_dst = (float*)alloc((size_t)n * sizeof(float));
    float* vsrc = (float*)alloc((size_t)n * sizeof(float));
    float* rbuf = (float*)alloc((size_t)n * sizeof(float));
    bf16_t* hA = (bf16_t*)alloc((size_t)n * 64 * sizeof(bf16_t));
    bf16_t* hX = (bf16_t*)alloc((size_t)n * 64 * sizeof(bf16_t));

    hipMemsetAsync(meta, 0, 32 * sizeof(int), stream);  // dsz + ssz only

    int gP = (E + 1023) / 1024;
    k_p0<<<gP, 256, 0, stream>>>(src, dst, dsz, ssz, nr, E);
    k_pscan<<<1, 64, 0, stream>>>(dsz, ssz, dbase, sbase, dcur, scur, nr);
    k_p1<<<gP, 256, 0, stream>>>(src, dst, dcur, scur, ebuf, sbuf, nr, E);
    k_hist<<<2 * nr * CHUNKS, 256, 0, stream>>>(ebuf, sbuf, dbase, sbase,
                                                cntC_in, cntC_out, nr, n);
    k_scan1<<<nb, 256, 0, stream>>>(cntC_in, cnt_tot_in, rowptr, blocksums, n);
    k_scan3<<<nb, 256, 0, stream>>>(rowptr, blocksums, cntC_in, cntC_out, cnt_tot_in,
                                    cursorC, norm_src, norm_dst, vsrc, nb, n, E);
    k_fillv2<<<nr * CHUNKS, 256, 0, stream>>>(ebuf, dbase, cursorC, colsrc, nr, n);

    // layer 0 (quarter-wave per node)
    k_layer0<<<(n + 15) / 16, 256, 0, stream>>>(rowptr, colsrc, vsrc, norm_dst, norm_src,
                                                W0, b0, hA, n);

    // layers 1,2: fused gather + MFMA dense
    int gfgd = (n + 63) / 64;
    k_fgd<0><<<gfgd, 256, 0, stream>>>(rowptr, colsrc, hA, norm_dst, norm_src,
                                       W1, b1, nullptr, hX, nullptr, n);
    k_fgd<1><<<gfgd, 256, 0, stream>>>(rowptr, colsrc, hX, norm_dst, nullptr,
                                       W2, b2, Wr, nullptr, rbuf, n);

    // readout
    k_mean<<<NGRAPHS, 256, 0, stream>>>(rbuf, n2g, br, out, n);
}

// Round 14
// 203.155 us; speedup vs baseline: 1.5189x; 1.0522x over previous
//
#include <hip/hip_runtime.h>
#include <hip/hip_bf16.h>

#define NGRAPHS 64
#define RANGE 8192
#define RSHIFT 13
#define CHUNKS 32

typedef unsigned short u16;
typedef unsigned int u32;
typedef unsigned long long u64;
typedef unsigned short bf16_t;
using s8v = __attribute__((ext_vector_type(8))) short;   // 8 bf16 (4 VGPRs)
using f4v = __attribute__((ext_vector_type(4))) float;   // MFMA accumulator

__device__ inline float bf2f(bf16_t u) { return __uint_as_float(((unsigned)u) << 16); }
__device__ inline bf16_t f2bf(float f) {
    unsigned x = __float_as_uint(f);
    return (bf16_t)((x + 0x7fffu + ((x >> 16) & 1u)) >> 16);  // RNE
}
__device__ inline void acc4(u64 v, float& a, float& b, float& c, float& d) {
    u32 lo = (u32)v, hi = (u32)(v >> 32);
    a += __uint_as_float(lo << 16);
    b += __uint_as_float(lo & 0xFFFF0000u);
    c += __uint_as_float(hi << 16);
    d += __uint_as_float(hi & 0xFFFF0000u);
}

// ============ init: bucket cursor bases (stride E per range) + gsum zero ============
__global__ void k_init(int* __restrict__ dcur, int* __restrict__ scur,
                       float* __restrict__ gsum, int E) {
    int t = threadIdx.x;
    if (t < 16) { dcur[t] = t * E; scur[t] = t * E; }
    gsum[t] = 0.0f;
}

// ============ partition edges by dst-range (and src by src-range); LDS local rank ============
__global__ void k_part(const int* __restrict__ src, const int* __restrict__ dst,
                       int* __restrict__ dcur, int* __restrict__ scur,
                       u32* __restrict__ ebuf, u16* __restrict__ sbuf, int nr, int E) {
    __shared__ int ldc[16], lsc[16], gdb[16], gsb[16];
    int tid = threadIdx.x;
    if (tid < 16) { ldc[tid] = 0; lsc[tid] = 0; }
    __syncthreads();
    int e4 = (blockIdx.x * 256 + tid) * 4;
    int s[4], d[4], pd[4], ps[4];
    int cnt = 0;
    if (e4 + 4 <= E) {
        int4 dv = *(const int4*)&dst[e4];
        int4 sv = *(const int4*)&src[e4];
        s[0] = sv.x; s[1] = sv.y; s[2] = sv.z; s[3] = sv.w;
        d[0] = dv.x; d[1] = dv.y; d[2] = dv.z; d[3] = dv.w;
        cnt = 4;
    } else {
        for (int e = e4; e < E; ++e) { s[cnt] = src[e]; d[cnt] = dst[e]; ++cnt; }
    }
    for (int i = 0; i < cnt; ++i) {
        pd[i] = atomicAdd(&ldc[d[i] >> RSHIFT], 1);   // LDS local rank
        ps[i] = atomicAdd(&lsc[s[i] >> RSHIFT], 1);
    }
    __syncthreads();
    if (tid < nr) {
        gdb[tid] = atomicAdd(&dcur[tid], ldc[tid]);   // ~14 global atomics/block
        gsb[tid] = atomicAdd(&scur[tid], lsc[tid]);
    }
    __syncthreads();
    for (int i = 0; i < cnt; ++i) {
        int db = d[i] >> RSHIFT, sb = s[i] >> RSHIFT;
        ebuf[gdb[db] + pd[i]] = ((u32)s[i] << 16) | (u32)d[i];
        sbuf[gsb[sb] + ps[i]] = (u16)s[i];
    }
}

// ============ histogram each (type, range, chunk) ============
__global__ void k_hist(const u32* __restrict__ ebuf, const u16* __restrict__ sbuf,
                       const int* __restrict__ dcur, const int* __restrict__ scur,
                       int* __restrict__ cntC_in, int* __restrict__ cntC_out,
                       int nr, int n, int E) {
    __shared__ int hist[RANGE];
    int tid = threadIdx.x, bid = blockIdx.x;
    int type = bid / (nr * CHUNKS);
    int rem = bid - type * nr * CHUNKS;
    int r = rem / CHUNKS, c = rem - r * CHUNKS;
    for (int i = tid; i < RANGE; i += 256) hist[i] = 0;
    __syncthreads();
    int lo = r * RANGE;
    int seg0 = r * E;
    int seg1 = type ? scur[r] : dcur[r];
    int sz = seg1 - seg0;
    int ce0 = seg0 + (int)((long long)sz * c / CHUNKS);
    int ce1 = seg0 + (int)((long long)sz * (c + 1) / CHUNKS);
    int e = ce0 + tid;
    if (type == 0) {
        for (; e + 768 < ce1; e += 1024) {
            int k0 = ebuf[e] & 0xFFFF, k1 = ebuf[e + 256] & 0xFFFF;
            int k2 = ebuf[e + 512] & 0xFFFF, k3 = ebuf[e + 768] & 0xFFFF;
            atomicAdd(&hist[k0 - lo], 1); atomicAdd(&hist[k1 - lo], 1);
            atomicAdd(&hist[k2 - lo], 1); atomicAdd(&hist[k3 - lo], 1);
        }
        for (; e < ce1; e += 256) atomicAdd(&hist[(ebuf[e] & 0xFFFF) - lo], 1);
    } else {
        for (; e + 768 < ce1; e += 1024) {
            int k0 = sbuf[e], k1 = sbuf[e + 256], k2 = sbuf[e + 512], k3 = sbuf[e + 768];
            atomicAdd(&hist[k0 - lo], 1); atomicAdd(&hist[k1 - lo], 1);
            atomicAdd(&hist[k2 - lo], 1); atomicAdd(&hist[k3 - lo], 1);
        }
        for (; e < ce1; e += 256) atomicAdd(&hist[(int)sbuf[e] - lo], 1);
    }
    __syncthreads();
    int hi = min(n - lo, RANGE);
    int* __restrict__ outb = (type ? cntC_out : cntC_in) + (size_t)c * n + lo;
    for (int i = tid; i < hi; i += 256) outb[i] = hist[i];
}

__device__ inline int block_excl_scan(int v, int tid, int* wavesums, int* block_total) {
    int lane = tid & 63, wave = tid >> 6;
    int incl = v;
    #pragma unroll
    for (int off = 1; off < 64; off <<= 1) {
        int t = __shfl_up(incl, off);
        if (lane >= off) incl += t;
    }
    if (lane == 63) wavesums[wave] = incl;
    __syncthreads();
    int woff = 0;
    #pragma unroll
    for (int w = 0; w < 4; ++w) if (w < wave) woff += wavesums[w];
    *block_total = wavesums[0] + wavesums[1] + wavesums[2] + wavesums[3];
    return incl + woff - v;
}

__global__ void k_scan1(const int* __restrict__ cntC_in, int* __restrict__ cnt_tot_in,
                        int* __restrict__ rowptr, int* __restrict__ blocksums, int n) {
    __shared__ int wavesums[4];
    int tid = threadIdx.x;
    int idx = blockIdx.x * 256 + tid;
    int v = 0;
    if (idx < n) {
        #pragma unroll
        for (int k = 0; k < CHUNKS; ++k) v += cntC_in[(size_t)k * n + idx];
        cnt_tot_in[idx] = v;
    }
    int total;
    int excl = block_excl_scan(v, tid, wavesums, &total);
    if (idx < n) rowptr[idx] = excl;
    if (tid == 0) blocksums[blockIdx.x] = total;
}

// scan3 with scan2 folded in (nb <= 256)
__global__ void k_scan3(int* __restrict__ rowptr, const int* __restrict__ blocksums,
                        const int* __restrict__ cntC_in, const int* __restrict__ cntC_out,
                        const int* __restrict__ cnt_tot_in,
                        int* __restrict__ cursorC,
                        float* __restrict__ norm_src, float* __restrict__ norm_dst,
                        float* __restrict__ vsrc, int nb, int n, int E) {
    __shared__ int wavesums[4];
    __shared__ int sbs[256];
    int tid = threadIdx.x;
    int bv = (tid < nb) ? blocksums[tid] : 0;
    int total;
    int bexcl = block_excl_scan(bv, tid, wavesums, &total);
    sbs[tid] = bexcl;
    __syncthreads();
    int blockoff = sbs[blockIdx.x];

    int idx = blockIdx.x * 256 + tid;
    if (idx < n) {
        int base = rowptr[idx] + blockoff;
        rowptr[idx] = base;
        int dout = 0;
        #pragma unroll
        for (int k = 0; k < CHUNKS; ++k) {
            cursorC[(size_t)k * n + idx] = base;
            base += cntC_in[(size_t)k * n + idx];
            dout += cntC_out[(size_t)k * n + idx];
        }
        float di = (float)cnt_tot_in[idx];
        float ns = rsqrtf(fmaxf((float)dout, 1.0f));
        norm_src[idx] = ns;
        norm_dst[idx] = rsqrtf(fmaxf(di, 1.0f));
        vsrc[idx] = di * ns;
    }
    if (idx == 0) rowptr[n] = E;
}

__global__ void k_fillv2(const u32* __restrict__ ebuf, const int* __restrict__ dcur,
                         const int* __restrict__ cursorC, u16* __restrict__ colsrc,
                         int nr, int n, int E) {
    __shared__ int cur[RANGE];
    int tid = threadIdx.x, bid = blockIdx.x;
    int r = bid / CHUNKS, c = bid - r * CHUNKS;
    int lo = r * RANGE, hi = min(n - lo, RANGE);
    for (int i = tid; i < hi; i += 256) cur[i] = cursorC[(size_t)c * n + lo + i];
    __syncthreads();
    int seg0 = r * E, seg1 = dcur[r];
    int sz = seg1 - seg0;
    int ce0 = seg0 + (int)((long long)sz * c / CHUNKS);
    int ce1 = seg0 + (int)((long long)sz * (c + 1) / CHUNKS);
    int e = ce0 + tid;
    for (; e + 768 < ce1; e += 1024) {
        u32 v0 = ebuf[e], v1 = ebuf[e + 256], v2 = ebuf[e + 512], v3 = ebuf[e + 768];
        colsrc[atomicAdd(&cur[(v0 & 0xFFFF) - lo], 1)] = (u16)(v0 >> 16);
        colsrc[atomicAdd(&cur[(v1 & 0xFFFF) - lo], 1)] = (u16)(v1 >> 16);
        colsrc[atomicAdd(&cur[(v2 & 0xFFFF) - lo], 1)] = (u16)(v2 >> 16);
        colsrc[atomicAdd(&cur[(v3 & 0xFFFF) - lo], 1)] = (u16)(v3 >> 16);
    }
    for (; e < ce1; e += 256) {
        u32 v = ebuf[e];
        colsrc[atomicAdd(&cur[(v & 0xFFFF) - lo], 1)] = (u16)(v >> 16);
    }
}

// ============ layer 0: quarter-wave per node, u64 feat stores ============
__global__ void k_layer0(const int* __restrict__ rowptr, const u16* __restrict__ colsrc,
                         const float* __restrict__ vsrc, const float* __restrict__ norm_dst,
                         const float* __restrict__ norm_src,
                         const float* __restrict__ W0, const float* __restrict__ b0,
                         bf16_t* __restrict__ out, int n) {
    int wave = threadIdx.x >> 6, lane = threadIdx.x & 63;
    int qw = lane >> 4, f = lane & 15;
    int i = blockIdx.x * 16 + wave * 4 + qw;
    if (i >= n) return;
    int p0 = rowptr[i], pe = rowptr[i + 1];
    float s = 0.0f;
    for (int p = p0 + f; p < pe; p += 16) s += vsrc[colsrc[p]];
    #pragma unroll
    for (int off = 1; off < 16; off <<= 1) s += __shfl_xor(s, off);
    float nd = norm_dst[i], ns = norm_src[i];
    float4 w = ((const float4*)W0)[f];
    float4 bb = ((const float4*)b0)[f];
    float a = s * nd;
    float v0 = fmaxf(a * w.x + bb.x, 0.0f) * ns;
    float v1 = fmaxf(a * w.y + bb.y, 0.0f) * ns;
    float v2 = fmaxf(a * w.z + bb.z, 0.0f) * ns;
    float v3 = fmaxf(a * w.w + bb.w, 0.0f) * ns;
    u32 plo = ((u32)f2bf(v1) << 16) | (u32)f2bf(v0);
    u32 phi = ((u32)f2bf(v3) << 16) | (u32)f2bf(v2);
    *(u64*)&out[(size_t)i * 64 + f * 4] = ((u64)phi << 32) | plo;
}

// ============ FUSED gather -> LDS A-strip -> MFMA dense ============
// FUSE_DOT=1: epilogue accumulates per-graph dot sums into LDS then gsum (atomic).
template <int FUSE_DOT>
__global__ __launch_bounds__(256, 4)
void k_fgd(const int* __restrict__ rowptr, const u16* __restrict__ colsrc,
           const bf16_t* __restrict__ hin, const float* __restrict__ norm_dst,
           const float* __restrict__ norm_src,
           const float* __restrict__ W, const float* __restrict__ b,
           const float* __restrict__ Wr, const int* __restrict__ n2g,
           bf16_t* __restrict__ hout, float* __restrict__ gsum, int n) {
    __shared__ bf16_t Wbf[64 * 64];
    __shared__ float bs[64];
    __shared__ u32 astrip[64 * 36];   // 64 rows, stride 36 u32 = 144 B
    __shared__ float gacc[64];
    int tid = threadIdx.x;
    #pragma unroll
    for (int it = 0; it < 16; ++it) {
        int idx = tid + it * 256;
        Wbf[idx] = f2bf(W[idx]);
    }
    if (tid < 64) { bs[tid] = b[tid]; if (FUSE_DOT) gacc[tid] = 0.0f; }
    __syncthreads();

    int wave = tid >> 6, lane = tid & 63;
    int quad = lane >> 4, l16 = lane & 15;
    int qw = lane >> 4, f = lane & 15, qb = qw << 4;

    int m0 = (blockIdx.x * 4 + wave) * 16;
    bool active = (m0 < n);
    if (!FUSE_DOT && !active) return;

    if (active) {
        // B fragments from LDS (one-time)
        s8v bfrag[4][2];
        #pragma unroll
        for (int t = 0; t < 4; ++t)
            #pragma unroll
            for (int c = 0; c < 2; ++c)
                #pragma unroll
                for (int jj = 0; jj < 8; ++jj)
                    bfrag[t][c][jj] = (short)Wbf[(c * 32 + qw * 8 + jj) * 64 + t * 16 + l16];

        const u64* __restrict__ hp = (const u64*)hin;  // row c -> c*16 + f

        // gather 16 rows, 4 at a time (quarter-waves independent)
        for (int t = 0; t < 16; t += 4) {
            int i = m0 + t + qw;
            int p0 = 0, deg = 0;
            if (i < n) { p0 = rowptr[i]; deg = rowptr[i + 1] - p0; }
            float s0 = 0.f, s1 = 0.f, s2 = 0.f, s3 = 0.f;
            float t0 = 0.f, t1 = 0.f, t2 = 0.f, t3 = 0.f;
            for (int cb = 0; cb < deg; cb += 16) {
                int m = min(16, deg - cb);
                int col = (f < m) ? (int)colsrc[p0 + cb + f] : 0;
                int e = 0;
                for (; e + 8 <= m; e += 8) {
                    int c0 = __shfl(col, qb + e),     c1 = __shfl(col, qb + e + 1);
                    int c2 = __shfl(col, qb + e + 2), c3 = __shfl(col, qb + e + 3);
                    int c4 = __shfl(col, qb + e + 4), c5 = __shfl(col, qb + e + 5);
                    int c6 = __shfl(col, qb + e + 6), c7 = __shfl(col, qb + e + 7);
                    u64 v0 = hp[c0 * 16 + f], v1 = hp[c1 * 16 + f];
                    u64 v2 = hp[c2 * 16 + f], v3 = hp[c3 * 16 + f];
                    u64 v4 = hp[c4 * 16 + f], v5 = hp[c5 * 16 + f];
                    u64 v6 = hp[c6 * 16 + f], v7 = hp[c7 * 16 + f];
                    acc4(v0, s0, s1, s2, s3); acc4(v1, t0, t1, t2, t3);
                    acc4(v2, s0, s1, s2, s3); acc4(v3, t0, t1, t2, t3);
                    acc4(v4, s0, s1, s2, s3); acc4(v5, t0, t1, t2, t3);
                    acc4(v6, s0, s1, s2, s3); acc4(v7, t0, t1, t2, t3);
                }
                for (; e < m; ++e) {
                    int c = __shfl(col, qb + e);
                    acc4(hp[c * 16 + f], s0, s1, s2, s3);
                }
            }
            u64 packed = 0;
            if (i < n) {
                float nd = norm_dst[i];
                float f0 = (s0 + t0) * nd, f1 = (s1 + t1) * nd;
                float f2 = (s2 + t2) * nd, f3 = (s3 + t3) * nd;
                u32 plo = ((u32)f2bf(f1) << 16) | (u32)f2bf(f0);
                u32 phi = ((u32)f2bf(f3) << 16) | (u32)f2bf(f2);
                packed = ((u64)phi << 32) | plo;
            }
            *(u64*)&astrip[(wave * 16 + t + qw) * 36 + f * 2] = packed;
        }
        asm volatile("s_waitcnt lgkmcnt(0)" ::: "memory");  // wave-local LDS RAW fence

        const char* ap = (const char*)astrip + (wave * 16 + l16) * 144 + quad * 16;
        s8v a0 = *(const s8v*)ap;
        s8v a1 = *(const s8v*)(ap + 64);

        f4v acc[4];
        #pragma unroll
        for (int t = 0; t < 4; ++t) { acc[t][0] = 0.f; acc[t][1] = 0.f; acc[t][2] = 0.f; acc[t][3] = 0.f; }
        #pragma unroll
        for (int t = 0; t < 4; ++t) {
            acc[t] = __builtin_amdgcn_mfma_f32_16x16x32_bf16(a0, bfrag[t][0], acc[t], 0, 0, 0);
            acc[t] = __builtin_amdgcn_mfma_f32_16x16x32_bf16(a1, bfrag[t][1], acc[t], 0, 0, 0);
        }

        if (FUSE_DOT) {
            float p0 = 0.f, p1 = 0.f, p2 = 0.f, p3 = 0.f;
            #pragma unroll
            for (int t = 0; t < 4; ++t) {
                float wr = Wr[t * 16 + l16];
                float bias = bs[t * 16 + l16];
                p0 = fmaf(fmaxf(acc[t][0] + bias, 0.f), wr, p0);
                p1 = fmaf(fmaxf(acc[t][1] + bias, 0.f), wr, p1);
                p2 = fmaf(fmaxf(acc[t][2] + bias, 0.f), wr, p2);
                p3 = fmaf(fmaxf(acc[t][3] + bias, 0.f), wr, p3);
            }
            float pr[4] = {p0, p1, p2, p3};
            #pragma unroll
            for (int r = 0; r < 4; ++r) {
                float v = pr[r];
                v += __shfl_xor(v, 1); v += __shfl_xor(v, 2);
                v += __shfl_xor(v, 4); v += __shfl_xor(v, 8);
                int i = m0 + quad * 4 + r;
                if (l16 == 0 && i < n) atomicAdd(&gacc[n2g[i]], v);  // LDS atomic
            }
        } else {
            float ns[4];
            #pragma unroll
            for (int r = 0; r < 4; ++r) {
                int i = m0 + quad * 4 + r;
                ns[r] = norm_src[i < n ? i : n - 1];
            }
            #pragma unroll
            for (int t = 0; t < 4; ++t) {
                float bias = bs[t * 16 + l16];
                #pragma unroll
                for (int r = 0; r < 4; ++r) {
                    int i = m0 + quad * 4 + r;
                    if (i < n) {
                        float v = fmaxf(acc[t][r] + bias, 0.f) * ns[r];
                        hout[(size_t)i * 64 + t * 16 + l16] = f2bf(v);
                    }
                }
            }
        }
    }

    if (FUSE_DOT) {
        __syncthreads();
        if (tid < 64) {
            float v = gacc[tid];
            if (v != 0.0f) atomicAdd(&gsum[tid], v);   // ~2 nonzero graphs/block
        }
    }
}

// ============ finalize: out[g] = gsum[g]/count[g] + br ============
__global__ void k_fin(const float* __restrict__ gsum, const int* __restrict__ n2g,
                      const float* __restrict__ br, float* __restrict__ out, int n) {
    int g = threadIdx.x;
    int lo = 0, hi = n;
    while (lo < hi) { int mid = (lo + hi) >> 1; if (n2g[mid] < g) lo = mid + 1; else hi = mid; }
    int lo2 = 0, hi2 = n;
    int g1 = g + 1;
    while (lo2 < hi2) { int mid = (lo2 + hi2) >> 1; if (n2g[mid] < g1) lo2 = mid + 1; else hi2 = mid; }
    out[g] = gsum[g] / fmaxf((float)(lo2 - lo), 1.0f) + br[0];
}

extern "C" void kernel_launch(void* const* d_in, const int* in_sizes, int n_in,
                              void* d_out, int out_size, void* d_ws, size_t ws_size,
                              hipStream_t stream) {
    const int* src = (const int*)d_in[0];
    const int* dst = (const int*)d_in[1];
    const int* n2g = (const int*)d_in[2];
    const float* W0 = (const float*)d_in[3];
    const float* b0 = (const float*)d_in[4];
    const float* W1 = (const float*)d_in[5];
    const float* b1 = (const float*)d_in[6];
    const float* W2 = (const float*)d_in[7];
    const float* b2 = (const float*)d_in[8];
    const float* Wr = (const float*)d_in[9];
    const float* br = (const float*)d_in[10];
    float* out = (float*)d_out;

    int E = in_sizes[0];
    int n = in_sizes[2];               // 50000 (< 65536: u16 packing valid)
    int nb = (n + 255) / 256;          // 196 (<= 256 for merged scan)
    int nr = (n + RANGE - 1) / RANGE;  // 7

    char* base = (char*)d_ws;
    size_t off = 0;
    auto alloc = [&](size_t bytes) -> void* {
        off = (off + 255) & ~(size_t)255;
        void* p = base + off;
        off += bytes;
        return p;
    };
    int* meta = (int*)alloc(64 * sizeof(int));
    int* dcur = meta;         // 16 (cursor; base r*E)
    int* scur = meta + 16;    // 16
    float* gsum = (float*)alloc(64 * sizeof(float));
    u32* ebuf = (u32*)alloc((size_t)nr * E * sizeof(u32));
    u16* sbuf = (u16*)alloc((size_t)nr * E * sizeof(u16));
    int* cntC_in = (int*)alloc((size_t)CHUNKS * n * sizeof(int));
    int* cntC_out = (int*)alloc((size_t)CHUNKS * n * sizeof(int));
    int* cursorC = (int*)alloc((size_t)CHUNKS * n * sizeof(int));
    int* cnt_tot_in = (int*)alloc((size_t)n * sizeof(int));
    int* rowptr = (int*)alloc((size_t)(n + 1) * sizeof(int));
    int* blocksums = (int*)alloc(256 * sizeof(int));
    u16* colsrc = (u16*)alloc((size_t)E * sizeof(u16));
    float* norm_src = (float*)alloc((size_t)n * sizeof(float));
    float* norm_dst = (float*)alloc((size_t)n * sizeof(float));
    float* vsrc = (float*)alloc((size_t)n * sizeof(float));
    bf16_t* hA = (bf16_t*)alloc((size_t)n * 64 * sizeof(bf16_t));
    bf16_t* hX = (bf16_t*)alloc((size_t)n * 64 * sizeof(bf16_t));

    int gP = (E + 1023) / 1024;
    k_init<<<1, 64, 0, stream>>>(dcur, scur, gsum, E);
    k_part<<<gP, 256, 0, stream>>>(src, dst, dcur, scur, ebuf, sbuf, nr, E);
    k_hist<<<2 * nr * CHUNKS, 256, 0, stream>>>(ebuf, sbuf, dcur, scur,
                                                cntC_in, cntC_out, nr, n, E);
    k_scan1<<<nb, 256, 0, stream>>>(cntC_in, cnt_tot_in, rowptr, blocksums, n);
    k_scan3<<<nb, 256, 0, stream>>>(rowptr, blocksums, cntC_in, cntC_out, cnt_tot_in,
                                    cursorC, norm_src, norm_dst, vsrc, nb, n, E);
    k_fillv2<<<nr * CHUNKS, 256, 0, stream>>>(ebuf, dcur, cursorC, colsrc, nr, n, E);

    // layer 0 (quarter-wave per node)
    k_layer0<<<(n + 15) / 16, 256, 0, stream>>>(rowptr, colsrc, vsrc, norm_dst, norm_src,
                                                W0, b0, hA, n);

    // layers 1,2: fused gather + MFMA dense; layer 2 fuses Wr-dot + graph partial sums
    int gfgd = (n + 63) / 64;
    k_fgd<0><<<gfgd, 256, 0, stream>>>(rowptr, colsrc, hA, norm_dst, norm_src,
                                       W1, b1, nullptr, nullptr, hX, nullptr, n);
    k_fgd<1><<<gfgd, 256, 0, stream>>>(rowptr, colsrc, hX, norm_dst, nullptr,
                                       W2, b2, Wr, n2g, nullptr, gsum, n);

    // finalize
    k_fin<<<1, 64, 0, stream>>>(gsum, n2g, br, out, n);
}